// Round 2
// baseline (8737.923 us; speedup 1.0000x reference)
//
#include <hip/hip_runtime.h>
#include <math.h>

// Problem constants (fixed by reference):
//   x: (8,12,512,256) fp32  -> tokens T = 8*12*512 = 49152, D = 256
//   DEPTH=6, HEADS=4, DH=64, N(seq within attention)=512, batch-rows BL=96
#define T_TOK 49152
#define DMODEL 256
#define NSEQ 512
#define BLROWS 96
#define NHEADS 4
#define HDIM 64

// ---------------------------------------------------------------------------
// LayerNorm: one wave (64 lanes) per 256-float row, 4 rows per block.
// out = (x - mean) / sqrt(var + 1e-5) * s + b.  Safe to run in-place.
// ---------------------------------------------------------------------------
__global__ __launch_bounds__(256) void ln_kernel(const float* __restrict__ in,
                                                 float* __restrict__ out,
                                                 const float* __restrict__ s,
                                                 const float* __restrict__ b) {
    int wave = threadIdx.x >> 6;
    int lane = threadIdx.x & 63;
    size_t row = (size_t)blockIdx.x * 4 + wave;
    const float4* in4 = reinterpret_cast<const float4*>(in + row * DMODEL);
    float4 v = in4[lane];
    float sum = v.x + v.y + v.z + v.w;
    float ssq = v.x * v.x + v.y * v.y + v.z * v.z + v.w * v.w;
#pragma unroll
    for (int m = 1; m <= 32; m <<= 1) {
        sum += __shfl_xor(sum, m, 64);
        ssq += __shfl_xor(ssq, m, 64);
    }
    float mean = sum * (1.0f / 256.0f);
    float var = ssq * (1.0f / 256.0f) - mean * mean;
    float rstd = rsqrtf(var + 1e-5f);
    float4 sv = reinterpret_cast<const float4*>(s)[lane];
    float4 bv = reinterpret_cast<const float4*>(b)[lane];
    float4 o;
    o.x = (v.x - mean) * rstd * sv.x + bv.x;
    o.y = (v.y - mean) * rstd * sv.y + bv.y;
    o.z = (v.z - mean) * rstd * sv.z + bv.z;
    o.w = (v.w - mean) * rstd * sv.w + bv.w;
    reinterpret_cast<float4*>(out + row * DMODEL)[lane] = o;
}

// ---------------------------------------------------------------------------
// fp32 GEMM: C[M x N] = A[M x K] @ W[K x N] + bias, optional epilogue.
// 128x128 tile, 256 threads, 8x8 acc per thread, BK=32.
// EPI: 0 = bias only, 1 = gelu(tanh approx), 2 = +residual R
// M%128 == N%128 == K%32 == 0 for every call here.
// ---------------------------------------------------------------------------
template <int EPI>
__global__ __launch_bounds__(256) void gemm_kernel(const float* __restrict__ A,
                                                   const float* __restrict__ W,
                                                   const float* __restrict__ bias,
                                                   const float* __restrict__ R,
                                                   float* __restrict__ C,
                                                   int K, int N) {
    __shared__ float As[32][132];  // [k][m], pad 132: conflict-free b128 reads
    __shared__ float Ws[32][128];  // [k][n]
    const int t0 = blockIdx.x * 128;
    const int n0 = blockIdx.y * 128;
    const int tid = threadIdx.x;
    const int tc = tid & 15;   // output col group (8 cols)
    const int tr = tid >> 4;   // output row group (8 rows)

    float acc[8][8];
#pragma unroll
    for (int i = 0; i < 8; ++i)
#pragma unroll
        for (int j = 0; j < 8; ++j) acc[i][j] = 0.0f;

    const float* Ag = A + (size_t)t0 * K;
    const float* Wg = W + n0;

    for (int k0 = 0; k0 < K; k0 += 32) {
        // Stage A tile (128 rows x 32 k), transposed into As[k][m]
#pragma unroll
        for (int it = 0; it < 4; ++it) {
            int idx = tid + it * 256;         // 0..1023
            int row = idx >> 3, kg = idx & 7; // 128 rows x 8 float4-groups
            float4 a = *reinterpret_cast<const float4*>(Ag + (size_t)row * K + k0 + kg * 4);
            As[kg * 4 + 0][row] = a.x;
            As[kg * 4 + 1][row] = a.y;
            As[kg * 4 + 2][row] = a.z;
            As[kg * 4 + 3][row] = a.w;
        }
        // Stage W tile (32 k x 128 n), natural layout
#pragma unroll
        for (int it = 0; it < 4; ++it) {
            int idx = tid + it * 256;
            int kr = idx >> 5, ng = idx & 31; // 32 k x 32 float4-groups
            float4 w = *reinterpret_cast<const float4*>(Wg + (size_t)(k0 + kr) * N + ng * 4);
            *reinterpret_cast<float4*>(&Ws[kr][ng * 4]) = w;
        }
        __syncthreads();
#pragma unroll
        for (int kk = 0; kk < 32; ++kk) {
            float a[8], w[8];
            *(float4*)&a[0] = *(const float4*)&As[kk][8 * tr];
            *(float4*)&a[4] = *(const float4*)&As[kk][8 * tr + 4];
            *(float4*)&w[0] = *(const float4*)&Ws[kk][8 * tc];
            *(float4*)&w[4] = *(const float4*)&Ws[kk][8 * tc + 4];
#pragma unroll
            for (int i = 0; i < 8; ++i)
#pragma unroll
                for (int j = 0; j < 8; ++j) acc[i][j] = fmaf(a[i], w[j], acc[i][j]);
        }
        __syncthreads();
    }

    float bs[8];
    *(float4*)&bs[0] = *(const float4*)(bias + n0 + 8 * tc);
    *(float4*)&bs[4] = *(const float4*)(bias + n0 + 8 * tc + 4);
#pragma unroll
    for (int i = 0; i < 8; ++i) {
        size_t t = (size_t)t0 + 8 * tr + i;
        float v[8];
#pragma unroll
        for (int j = 0; j < 8; ++j) {
            float c = acc[i][j] + bs[j];
            if (EPI == 1) {
                // jax.nn.gelu (approximate=True, tanh form)
                c = 0.5f * c * (1.0f + tanhf(0.7978845608028654f * (c + 0.044715f * c * c * c)));
            }
            v[j] = c;
        }
        if (EPI == 2) {
            float4 r0 = *(const float4*)(R + t * N + n0 + 8 * tc);
            float4 r1 = *(const float4*)(R + t * N + n0 + 8 * tc + 4);
            v[0] += r0.x; v[1] += r0.y; v[2] += r0.z; v[3] += r0.w;
            v[4] += r1.x; v[5] += r1.y; v[6] += r1.z; v[7] += r1.w;
        }
        *(float4*)(C + t * N + n0 + 8 * tc) = *(float4*)&v[0];
        *(float4*)(C + t * N + n0 + 8 * tc + 4) = *(float4*)&v[4];
    }
}

// ---------------------------------------------------------------------------
// Fused flash-style attention for one (batch-row, head, 64-row q-block).
// qkv: [BLC*512 x 768] (q|k|v, head h at cols h*64.. of its third) chunk-local
// rel: [1023 x 4] slice for this layer; bias[i][j] = rel[(i-j+511)*4 + h]
// o:   [BLC*512 x 256] chunk-local, head h writes cols h*64..h*64+63
// Block: 256 threads; thread (tr,tc): tr=tid/16 owns 4 q-rows, tc=tid%16 owns
// 4 k-cols (scores) / 4 dh-cols (output). Online softmax across 16 tc lanes.
// LDS: Kt and Ps share one buffer (Kt dead once S is in registers) -> 55 KB.
// ---------------------------------------------------------------------------
__global__ __launch_bounds__(256) void attn_kernel(const float* __restrict__ qkv,
                                                   const float* __restrict__ rel,
                                                   float* __restrict__ o) {
    __shared__ float Qt[64][68];    // [dh][i] transposed, padded
    __shared__ float KtPs[64][68];  // Kt: [dh][j]  then reused as  Ps: [i][j]
    __shared__ float Vs[64][68];    // [j][dh] natural
    __shared__ float rl[1024];      // rel-pos bias for this head

    const int qb = blockIdx.x;            // 0..7 (q block of 64 rows)
    const int pair = blockIdx.y;          // bl*4 + head, chunk-local
    const int bl = pair >> 2, hh = pair & 3;
    const int tid = threadIdx.x;
    const int tc = tid & 15, tr = tid >> 4;
    const size_t base = (size_t)bl * NSEQ * 768;
    const int qoff = hh * 64, koff = 256 + hh * 64, voff = 512 + hh * 64;
    const int i0 = qb * 64;

    for (int i = tid; i < 1023; i += 256) rl[i] = rel[(size_t)i * 4 + hh];

#pragma unroll
    for (int it = 0; it < 4; ++it) {
        int idx = tid + it * 256;
        int row = idx >> 4, dg = idx & 15;
        float4 q = *(const float4*)(qkv + base + (size_t)(i0 + row) * 768 + qoff + dg * 4);
        Qt[dg * 4 + 0][row] = q.x;
        Qt[dg * 4 + 1][row] = q.y;
        Qt[dg * 4 + 2][row] = q.z;
        Qt[dg * 4 + 3][row] = q.w;
    }

    float m_i[4], l_i[4], Oa[4][4];
#pragma unroll
    for (int i = 0; i < 4; ++i) {
        m_i[i] = -1e30f;
        l_i[i] = 0.0f;
#pragma unroll
        for (int j = 0; j < 4; ++j) Oa[i][j] = 0.0f;
    }

    for (int kt = 0; kt < 8; ++kt) {
        __syncthreads();  // prev iteration's readers of KtPs/Vs done
#pragma unroll
        for (int it = 0; it < 4; ++it) {
            int idx = tid + it * 256;
            int row = idx >> 4, dg = idx & 15;
            float4 k = *(const float4*)(qkv + base + (size_t)(kt * 64 + row) * 768 + koff + dg * 4);
            KtPs[dg * 4 + 0][row] = k.x;
            KtPs[dg * 4 + 1][row] = k.y;
            KtPs[dg * 4 + 2][row] = k.z;
            KtPs[dg * 4 + 3][row] = k.w;
            float4 v = *(const float4*)(qkv + base + (size_t)(kt * 64 + row) * 768 + voff + dg * 4);
            *(float4*)&Vs[row][dg * 4] = v;
        }
        __syncthreads();

        // S = (Q @ K^T) * scale + bias   (64x64 tile, 4x4 per thread)
        float s[4][4];
#pragma unroll
        for (int i = 0; i < 4; ++i)
#pragma unroll
            for (int j = 0; j < 4; ++j) s[i][j] = 0.0f;
#pragma unroll 8
        for (int d = 0; d < 64; ++d) {
            float qv[4], kv[4];
            *(float4*)qv = *(const float4*)&Qt[d][4 * tr];
            *(float4*)kv = *(const float4*)&KtPs[d][4 * tc];
#pragma unroll
            for (int i = 0; i < 4; ++i)
#pragma unroll
                for (int j = 0; j < 4; ++j) s[i][j] = fmaf(qv[i], kv[j], s[i][j]);
        }
        float p[4][4];
#pragma unroll
        for (int i = 0; i < 4; ++i) {
            int gi = i0 + 4 * tr + i;
#pragma unroll
            for (int j = 0; j < 4; ++j) {
                int gj = kt * 64 + 4 * tc + j;
                s[i][j] = s[i][j] * 0.125f + rl[gi - gj + 511];
            }
            // online softmax for this row (16 tc lanes hold the row)
            float rmax = fmaxf(fmaxf(s[i][0], s[i][1]), fmaxf(s[i][2], s[i][3]));
#pragma unroll
            for (int m = 1; m <= 8; m <<= 1) rmax = fmaxf(rmax, __shfl_xor(rmax, m, 64));
            float mn = fmaxf(m_i[i], rmax);
            float corr = expf(m_i[i] - mn);
            float psum = 0.0f;
#pragma unroll
            for (int j = 0; j < 4; ++j) {
                p[i][j] = expf(s[i][j] - mn);
                psum += p[i][j];
            }
#pragma unroll
            for (int m = 1; m <= 8; m <<= 1) psum += __shfl_xor(psum, m, 64);
            l_i[i] = l_i[i] * corr + psum;
            m_i[i] = mn;
#pragma unroll
            for (int j = 0; j < 4; ++j) Oa[i][j] *= corr;
        }
        __syncthreads();  // all threads done reading Kt -> safe to reuse as Ps
#pragma unroll
        for (int i = 0; i < 4; ++i) *(float4*)&KtPs[4 * tr + i][4 * tc] = *(float4*)&p[i][0];
        __syncthreads();

        // O += P @ V
#pragma unroll 8
        for (int kk = 0; kk < 64; ++kk) {
            float pv[4];
#pragma unroll
            for (int i = 0; i < 4; ++i) pv[i] = KtPs[4 * tr + i][kk];
            float4 vv = *(const float4*)&Vs[kk][4 * tc];
#pragma unroll
            for (int i = 0; i < 4; ++i) {
                Oa[i][0] = fmaf(pv[i], vv.x, Oa[i][0]);
                Oa[i][1] = fmaf(pv[i], vv.y, Oa[i][1]);
                Oa[i][2] = fmaf(pv[i], vv.z, Oa[i][2]);
                Oa[i][3] = fmaf(pv[i], vv.w, Oa[i][3]);
            }
        }
    }

#pragma unroll
    for (int i = 0; i < 4; ++i) {
        float inv = 1.0f / l_i[i];
        float4 ov;
        ov.x = Oa[i][0] * inv;
        ov.y = Oa[i][1] * inv;
        ov.z = Oa[i][2] * inv;
        ov.w = Oa[i][3] * inv;
        size_t t = (size_t)bl * NSEQ + i0 + 4 * tr + i;
        *(float4*)(o + t * DMODEL + hh * 64 + 4 * tc) = ov;
    }
}

// ---------------------------------------------------------------------------
// Orchestration.
// Residual stream h lives in d_out (T x 256 fp32 == output shape); final LN
// runs in-place (per-lane read-then-write, no cross-thread memory hazard).
// Scratch is chunked along the 96 batch-rows so it fits whatever ws_size the
// harness gives us:  per chunk  xnC (TC x 256) + big (TC x 1024) floats.
// NC is derived from ws_size only -> identical launch structure every call
// (graph-capture safe).  Min footprint (NC=96): 2.6 MB.
// ---------------------------------------------------------------------------
extern "C" void kernel_launch(void* const* d_in, const int* in_sizes, int n_in,
                              void* d_out, int out_size, void* d_ws, size_t ws_size,
                              hipStream_t stream) {
    const float* x       = (const float*)d_in[0];
    const float* ln1_s   = (const float*)d_in[1];
    const float* ln1_b   = (const float*)d_in[2];
    const float* qkv_w   = (const float*)d_in[3];
    const float* qkv_b   = (const float*)d_in[4];
    const float* proj_w  = (const float*)d_in[5];
    const float* proj_b  = (const float*)d_in[6];
    const float* rel_tab = (const float*)d_in[7];
    const float* ln2_s   = (const float*)d_in[8];
    const float* ln2_b   = (const float*)d_in[9];
    const float* w1      = (const float*)d_in[10];
    const float* b1      = (const float*)d_in[11];
    const float* w2      = (const float*)d_in[12];
    const float* b2      = (const float*)d_in[13];
    const float* lnf_s   = (const float*)d_in[14];
    const float* lnf_b   = (const float*)d_in[15];

    float* h = (float*)d_out;          // residual stream lives in d_out
    float* ws = (float*)d_ws;

    // Pick the largest chunk (fewest launches) whose scratch fits ws_size.
    static const int cands[12] = {1, 2, 3, 4, 6, 8, 12, 16, 24, 32, 48, 96};
    size_t availF = ws_size / sizeof(float);
    int NC = 96;
    for (int i = 0; i < 12; ++i) {
        size_t tc = (size_t)T_TOK / cands[i];
        if (tc * 1280 <= availF) { NC = cands[i]; break; }
    }
    const int TC  = T_TOK / NC;    // tokens per chunk (multiple of 512)
    const int BLC = BLROWS / NC;   // batch-rows per chunk
    float* xnC = ws;               // TC x 256
    float* big = ws + (size_t)TC * 256;  // TC x 768 (qkv) / TC x 1024 (mid)

    hipMemcpyAsync(h, x, (size_t)T_TOK * DMODEL * sizeof(float),
                   hipMemcpyDeviceToDevice, stream);

    dim3 blk(256);
    for (int d = 0; d < 6; ++d) {
        for (int c = 0; c < NC; ++c) {
            float* hc = h + (size_t)c * TC * DMODEL;
            // LN1 (chunk)
            ln_kernel<<<TC / 4, blk, 0, stream>>>(hc, xnC, ln1_s + d * 256, ln1_b + d * 256);
            // QKV: (TC x 256) @ (256 x 768)
            gemm_kernel<0><<<dim3(TC / 128, 6), blk, 0, stream>>>(
                xnC, qkv_w + (size_t)d * 256 * 768, qkv_b + (size_t)d * 768, nullptr, big, 256, 768);
            // Attention (chunk-local; writes o into xnC)
            attn_kernel<<<dim3(NSEQ / 64, BLC * NHEADS), blk, 0, stream>>>(
                big, rel_tab + (size_t)d * 1023 * 4, xnC);
            // proj + residual: hc += o @ Wp + bp
            gemm_kernel<2><<<dim3(TC / 128, 2), blk, 0, stream>>>(
                xnC, proj_w + (size_t)d * 256 * 256, proj_b + (size_t)d * 256, hc, hc, 256, 256);
        }
        for (int c = 0; c < NC; ++c) {
            float* hc = h + (size_t)c * TC * DMODEL;
            // LN2 (chunk)
            ln_kernel<<<TC / 4, blk, 0, stream>>>(hc, xnC, ln2_s + d * 256, ln2_b + d * 256);
            // FFN1 + gelu: (TC x 256) @ (256 x 1024)
            gemm_kernel<1><<<dim3(TC / 128, 8), blk, 0, stream>>>(
                xnC, w1 + (size_t)d * 256 * 1024, b1 + (size_t)d * 1024, nullptr, big, 256, 1024);
            // FFN2 + residual: hc += mid @ W2 + b2
            gemm_kernel<2><<<dim3(TC / 128, 2), blk, 0, stream>>>(
                big, w2 + (size_t)d * 1024 * 256, b2 + (size_t)d * 256, hc, hc, 1024, 256);
        }
    }
    // final LN, in-place on d_out
    ln_kernel<<<T_TOK / 4, blk, 0, stream>>>(h, h, lnf_s, lnf_b);
}

// Round 3
// 5398.292 us; speedup vs baseline: 1.6186x; 1.6186x over previous
//
#include <hip/hip_runtime.h>
#include <math.h>

// Problem constants (fixed by reference):
//   x: (8,12,512,256) fp32 -> tokens T = 8*12*512 = 49152, D = 256
//   DEPTH=6, HEADS=4, DH=64, N(seq)=512, batch-rows BL=96
#define T_TOK 49152
#define DMODEL 256
#define NSEQ 512
#define BLROWS 96

typedef unsigned short ushortT;
using frag_ab = __attribute__((ext_vector_type(8))) short;   // 8 bf16
using f32x4   = __attribute__((ext_vector_type(4))) float;   // 4 fp32 acc

__device__ __forceinline__ ushortT f2b(float f) {
    union { float f; unsigned int u; } v; v.f = f;
    unsigned int u = v.u;
    u += 0x7FFFu + ((u >> 16) & 1u);   // RNE
    return (ushortT)(u >> 16);
}
__device__ __forceinline__ float b2f(ushortT h) {
    union { unsigned int u; float f; } v; v.u = ((unsigned int)h) << 16;
    return v.f;
}

// ---------------------------------------------------------------------------
// Weight prep (once per launch): fp32 W[K][N] -> bf16 tiles [nb][ks][n:128][k:64]
// contiguous 8192-ushort tiles, ordered tt = nb*KS + ks.
// Layer bases (ushorts): qkv d*196608 | proj 1179648+d*65536 |
//                        w1 1572864+d*262144 | w2 3145728+d*262144 ; end 4718592
// ---------------------------------------------------------------------------
__global__ __launch_bounds__(256) void wprep_kernel(const float* __restrict__ qkv_w,
                                                    const float* __restrict__ proj_w,
                                                    const float* __restrict__ w1,
                                                    const float* __restrict__ w2,
                                                    ushortT* __restrict__ out) {
    __shared__ float Ls[64][132];
    int bid = blockIdx.x;
    int d = bid / 96, t = bid % 96;
    const float* src; int N, KS; size_t dbase; int tt;
    if (t < 24)      { src = qkv_w  + (size_t)d * 256 * 768;  N = 768;  KS = 4;  dbase = (size_t)d * 196608;            tt = t;      }
    else if (t < 32) { src = proj_w + (size_t)d * 256 * 256;  N = 256;  KS = 4;  dbase = 1179648 + (size_t)d * 65536;   tt = t - 24; }
    else if (t < 64) { src = w1     + (size_t)d * 256 * 1024; N = 1024; KS = 4;  dbase = 1572864 + (size_t)d * 262144;  tt = t - 32; }
    else             { src = w2     + (size_t)d * 1024 * 256; N = 256;  KS = 16; dbase = 3145728 + (size_t)d * 262144;  tt = t - 64; }
    int nb = tt / KS, ks = tt % KS;
    int k0 = ks * 64, n0 = nb * 128;
    int tid = threadIdx.x;
#pragma unroll
    for (int i = 0; i < 8; ++i) {
        int fidx = tid + i * 256;            // 0..2047 float4s of the 64x128 tile
        int kk = fidx >> 5, ng = fidx & 31;
        float4 v = *(const float4*)(src + (size_t)(k0 + kk) * N + n0 + ng * 4);
        *(float4*)&Ls[kk][ng * 4] = v;
    }
    __syncthreads();
    int n = tid & 127, kh = tid >> 7;
    ushortT* dst = out + dbase + (size_t)tt * 8192 + n * 64 + kh * 32;
    ushortT tmp[32];
#pragma unroll
    for (int j = 0; j < 32; ++j) tmp[j] = f2b(Ls[kh * 32 + j][n]);
#pragma unroll
    for (int u = 0; u < 4; ++u) *(uint4*)(dst + u * 8) = *(uint4*)(tmp + u * 8);
}

// ---------------------------------------------------------------------------
// LayerNorm: one wave per 256-float row. OB: bf16 out (for GEMM A), else fp32.
// ---------------------------------------------------------------------------
template <bool OB>
__global__ __launch_bounds__(256) void ln_kernel(const float* __restrict__ in,
                                                 void* __restrict__ out,
                                                 const float* __restrict__ s,
                                                 const float* __restrict__ b) {
    int wave = threadIdx.x >> 6;
    int lane = threadIdx.x & 63;
    size_t row = (size_t)blockIdx.x * 4 + wave;
    float4 v = reinterpret_cast<const float4*>(in + row * DMODEL)[lane];
    float sum = v.x + v.y + v.z + v.w;
    float ssq = v.x * v.x + v.y * v.y + v.z * v.z + v.w * v.w;
#pragma unroll
    for (int m = 1; m <= 32; m <<= 1) {
        sum += __shfl_xor(sum, m, 64);
        ssq += __shfl_xor(ssq, m, 64);
    }
    float mean = sum * (1.0f / 256.0f);
    float var = ssq * (1.0f / 256.0f) - mean * mean;
    float rstd = rsqrtf(var + 1e-5f);
    float4 sv = reinterpret_cast<const float4*>(s)[lane];
    float4 bv = reinterpret_cast<const float4*>(b)[lane];
    float o0 = (v.x - mean) * rstd * sv.x + bv.x;
    float o1 = (v.y - mean) * rstd * sv.y + bv.y;
    float o2 = (v.z - mean) * rstd * sv.z + bv.z;
    float o3 = (v.w - mean) * rstd * sv.w + bv.w;
    if (OB) {
        ushortT* po = (ushortT*)out + row * DMODEL + lane * 4;
        ushort4 ov; ov.x = f2b(o0); ov.y = f2b(o1); ov.z = f2b(o2); ov.w = f2b(o3);
        *(ushort4*)po = ov;
    } else {
        float4 ov; ov.x = o0; ov.y = o1; ov.z = o2; ov.w = o3;
        reinterpret_cast<float4*>((float*)out + row * DMODEL)[lane] = ov;
    }
}

// ---------------------------------------------------------------------------
// bf16 MFMA GEMM: C[M x N] = A[M x K](bf16) @ W(tiled bf16) + bias.
// 128x128 tile, BK=64, 4 waves in 2x2, each wave 64x64 (4x4 frags 16x16x32).
// LDS: Als/Bls [row:128][k:64] bf16, XOR-swizzled 16B units (u ^= row&7).
// EPI: 0 bias -> bf16 | 1 bias+gelu -> bf16 | 2 bias+residual(in-place f32 R)
// ---------------------------------------------------------------------------
template <int EPI>
__global__ __launch_bounds__(256) void gemm_bf16(const ushortT* __restrict__ A,
                                                 const ushortT* __restrict__ Wt,
                                                 const float* __restrict__ bias,
                                                 float* __restrict__ R,
                                                 ushortT* __restrict__ Cb,
                                                 int K, int N) {
    __shared__ ushortT Als[128 * 64];
    __shared__ ushortT Bls[128 * 64];
    const int m0 = blockIdx.x * 128, nb = blockIdx.y, n0 = nb * 128;
    const int tid = threadIdx.x, lane = tid & 63, wave = tid >> 6;
    const int wr = wave >> 1, wc = wave & 1;
    const int KS = K >> 6;

    // staging: thread t -> LDS row t>>1 (A: token row / B: out col), half t&1
    const int srow = tid >> 1, shalf = tid & 1;
    const ushortT* Abase = A + (size_t)(m0 + srow) * K + shalf * 32;
    const ushortT* Bbase = Wt + (size_t)nb * KS * 8192 + srow * 64 + shalf * 32;

    uint4 aq[4], bq[4];
    {
        const uint4* ap = (const uint4*)Abase;
        const uint4* bp = (const uint4*)Bbase;
#pragma unroll
        for (int u = 0; u < 4; ++u) { aq[u] = ap[u]; bq[u] = bp[u]; }
    }

    f32x4 acc[4][4];
#pragma unroll
    for (int i = 0; i < 4; ++i)
#pragma unroll
        for (int j = 0; j < 4; ++j) acc[i][j] = (f32x4)0.0f;

    for (int ks = 0; ks < KS; ++ks) {
        __syncthreads();
#pragma unroll
        for (int u = 0; u < 4; ++u) {
            int ku = shalf * 4 + u;
            int off = srow * 64 + ((ku ^ (srow & 7)) << 3);
            *(uint4*)&Als[off] = aq[u];
            *(uint4*)&Bls[off] = bq[u];
        }
        __syncthreads();
        if (ks + 1 < KS) {
            const uint4* ap = (const uint4*)(Abase + (ks + 1) * 64);
            const uint4* bp = (const uint4*)(Bbase + (size_t)(ks + 1) * 8192);
#pragma unroll
            for (int u = 0; u < 4; ++u) { aq[u] = ap[u]; bq[u] = bp[u]; }
        }
#pragma unroll
        for (int kst = 0; kst < 2; ++kst) {
            frag_ab af[4], bf[4];
            int ku = kst * 4 + (lane >> 4);
#pragma unroll
            for (int f = 0; f < 4; ++f) {
                int row = wr * 64 + f * 16 + (lane & 15);
                af[f] = *(frag_ab*)&Als[row * 64 + ((ku ^ (row & 7)) << 3)];
                int col = wc * 64 + f * 16 + (lane & 15);
                bf[f] = *(frag_ab*)&Bls[col * 64 + ((ku ^ (col & 7)) << 3)];
            }
#pragma unroll
            for (int mf = 0; mf < 4; ++mf)
#pragma unroll
                for (int nf = 0; nf < 4; ++nf)
                    acc[mf][nf] = __builtin_amdgcn_mfma_f32_16x16x32_bf16(
                        af[mf], bf[nf], acc[mf][nf], 0, 0, 0);
        }
    }

    // epilogue: lane holds C[row = .. + (lane>>4)*4 + r][col = .. + (lane&15)]
    const int cg = lane >> 4, cl = lane & 15;
#pragma unroll
    for (int nf = 0; nf < 4; ++nf) {
        int col = n0 + wc * 64 + nf * 16 + cl;
        float bv = bias[col];
#pragma unroll
        for (int mf = 0; mf < 4; ++mf) {
#pragma unroll
            for (int r = 0; r < 4; ++r) {
                int row = m0 + wr * 64 + mf * 16 + cg * 4 + r;
                float c = acc[mf][nf][r] + bv;
                if (EPI == 1) {
                    // gelu(tanh) == x * sigmoid(2*0.79788456*(x+0.044715x^3))
                    c = c / (1.0f + __expf(-1.5957691216f * (c + 0.044715f * c * c * c)));
                }
                if (EPI == 2) {
                    float* p = R + (size_t)row * N + col;
                    *p = *p + c;
                } else {
                    Cb[(size_t)row * N + col] = f2b(c);
                }
            }
        }
    }
}

// ---------------------------------------------------------------------------
// Flash attention, fp32 math, bf16 in/out. One block per (bl, head, 64-q-rows).
// qkv: [rows][768] bf16 (q|k|v). o: [rows][256] bf16. rel: [1023][4] fp32.
// Qt/Kt staged transposed with 16B-unit XOR swizzle (unit ^= d>>2) to kill the
// 8-way scatter-write conflicts. LDS 51 KB -> 3 blocks/CU.
// ---------------------------------------------------------------------------
__global__ __launch_bounds__(256) void attn_kernel(const ushortT* __restrict__ qkv,
                                                   const float* __restrict__ rel,
                                                   ushortT* __restrict__ o) {
    __shared__ float Qt[64][68];    // [dh][token'] swizzled
    __shared__ float KtPs[64][68];  // Kt swizzled, then reused as Ps (plain)
    __shared__ float Vs[64][68];    // [token][dh] plain

    const int qb = blockIdx.x, pair = blockIdx.y;
    const int bl = pair >> 2, hh = pair & 3;
    const int tid = threadIdx.x, tc = tid & 15, tr = tid >> 4;
    const size_t base = (size_t)bl * NSEQ * 768;
    const int qoff = hh * 64, koff = 256 + hh * 64, voff = 512 + hh * 64;
    const int i0 = qb * 64;

#pragma unroll
    for (int it = 0; it < 4; ++it) {
        int idx = tid + it * 256;
        int row = idx >> 4, dg = idx & 15;
        ushort4 q = *(const ushort4*)(qkv + base + (size_t)(i0 + row) * 768 + qoff + dg * 4);
        int cs = (((row >> 2) ^ dg) << 2) + (row & 3);   // swizzled token col
        Qt[dg * 4 + 0][cs] = b2f(q.x);
        Qt[dg * 4 + 1][cs] = b2f(q.y);
        Qt[dg * 4 + 2][cs] = b2f(q.z);
        Qt[dg * 4 + 3][cs] = b2f(q.w);
    }

    float m_i[4], l_i[4], Oa[4][4];
#pragma unroll
    for (int i = 0; i < 4; ++i) {
        m_i[i] = -1e30f;
        l_i[i] = 0.0f;
#pragma unroll
        for (int j = 0; j < 4; ++j) Oa[i][j] = 0.0f;
    }

    for (int kt = 0; kt < 8; ++kt) {
        __syncthreads();  // prev readers of KtPs/Vs done
#pragma unroll
        for (int it = 0; it < 4; ++it) {
            int idx = tid + it * 256;
            int row = idx >> 4, dg = idx & 15;
            ushort4 k = *(const ushort4*)(qkv + base + (size_t)(kt * 64 + row) * 768 + koff + dg * 4);
            int cs = (((row >> 2) ^ dg) << 2) + (row & 3);
            KtPs[dg * 4 + 0][cs] = b2f(k.x);
            KtPs[dg * 4 + 1][cs] = b2f(k.y);
            KtPs[dg * 4 + 2][cs] = b2f(k.z);
            KtPs[dg * 4 + 3][cs] = b2f(k.w);
            ushort4 v = *(const ushort4*)(qkv + base + (size_t)(kt * 64 + row) * 768 + voff + dg * 4);
            float4 vf; vf.x = b2f(v.x); vf.y = b2f(v.y); vf.z = b2f(v.z); vf.w = b2f(v.w);
            *(float4*)&Vs[row][dg * 4] = vf;
        }
        __syncthreads();

        // S = (Q @ K^T) * scale + bias
        float s[4][4];
#pragma unroll
        for (int i = 0; i < 4; ++i)
#pragma unroll
            for (int j = 0; j < 4; ++j) s[i][j] = 0.0f;
#pragma unroll 8
        for (int d = 0; d < 64; ++d) {
            int key = d >> 2;
            float qv[4], kv[4];
            *(float4*)qv = *(const float4*)&Qt[d][(tr ^ key) << 2];
            *(float4*)kv = *(const float4*)&KtPs[d][(tc ^ key) << 2];
#pragma unroll
            for (int i = 0; i < 4; ++i)
#pragma unroll
                for (int j = 0; j < 4; ++j) s[i][j] = fmaf(qv[i], kv[j], s[i][j]);
        }
        float p[4][4];
#pragma unroll
        for (int i = 0; i < 4; ++i) {
            int gi = i0 + 4 * tr + i;
            int rbase = gi - (kt * 64 + 4 * tc) + 511;   // index for j=0
#pragma unroll
            for (int j = 0; j < 4; ++j)
                s[i][j] = s[i][j] * 0.125f + rel[(size_t)(rbase - j) * 4 + hh];
            float rmax = fmaxf(fmaxf(s[i][0], s[i][1]), fmaxf(s[i][2], s[i][3]));
#pragma unroll
            for (int m = 1; m <= 8; m <<= 1) rmax = fmaxf(rmax, __shfl_xor(rmax, m, 64));
            float mn = fmaxf(m_i[i], rmax);
            float corr = __expf(m_i[i] - mn);
            float psum = 0.0f;
#pragma unroll
            for (int j = 0; j < 4; ++j) {
                p[i][j] = __expf(s[i][j] - mn);
                psum += p[i][j];
            }
#pragma unroll
            for (int m = 1; m <= 8; m <<= 1) psum += __shfl_xor(psum, m, 64);
            l_i[i] = l_i[i] * corr + psum;
            m_i[i] = mn;
#pragma unroll
            for (int j = 0; j < 4; ++j) Oa[i][j] *= corr;
        }
        __syncthreads();  // Kt reads done -> reuse buffer as Ps (plain layout)
#pragma unroll
        for (int i = 0; i < 4; ++i) *(float4*)&KtPs[4 * tr + i][4 * tc] = *(float4*)&p[i][0];
        __syncthreads();

        // O += P @ V
#pragma unroll 8
        for (int kk = 0; kk < 64; ++kk) {
            float pv[4];
#pragma unroll
            for (int i = 0; i < 4; ++i) pv[i] = KtPs[4 * tr + i][kk];
            float4 vv = *(const float4*)&Vs[kk][4 * tc];
#pragma unroll
            for (int i = 0; i < 4; ++i) {
                Oa[i][0] = fmaf(pv[i], vv.x, Oa[i][0]);
                Oa[i][1] = fmaf(pv[i], vv.y, Oa[i][1]);
                Oa[i][2] = fmaf(pv[i], vv.z, Oa[i][2]);
                Oa[i][3] = fmaf(pv[i], vv.w, Oa[i][3]);
            }
        }
    }

#pragma unroll
    for (int i = 0; i < 4; ++i) {
        float inv = 1.0f / l_i[i];
        size_t t = (size_t)bl * NSEQ + i0 + 4 * tr + i;
        ushort4 ov;
        ov.x = f2b(Oa[i][0] * inv);
        ov.y = f2b(Oa[i][1] * inv);
        ov.z = f2b(Oa[i][2] * inv);
        ov.w = f2b(Oa[i][3] * inv);
        *(ushort4*)&o[t * DMODEL + hh * 64 + 4 * tc] = ov;
    }
}

// ---------------------------------------------------------------------------
// Orchestration. h (residual, fp32) lives in d_out. ws layout:
//   [0, 4718592) ushorts : pre-tiled bf16 weights (9.44 MB)
//   then per-chunk scratch (bf16): xnC TCx256 | big TCx1024 (qkv 768 / mid) |
//   oC TCx256  -> TC*3072 bytes. NC chosen from ws_size only (capture-stable).
//   NC=1 total: 160 MB.
// ---------------------------------------------------------------------------
extern "C" void kernel_launch(void* const* d_in, const int* in_sizes, int n_in,
                              void* d_out, int out_size, void* d_ws, size_t ws_size,
                              hipStream_t stream) {
    const float* x       = (const float*)d_in[0];
    const float* ln1_s   = (const float*)d_in[1];
    const float* ln1_b   = (const float*)d_in[2];
    const float* qkv_w   = (const float*)d_in[3];
    const float* qkv_b   = (const float*)d_in[4];
    const float* proj_w  = (const float*)d_in[5];
    const float* proj_b  = (const float*)d_in[6];
    const float* rel_tab = (const float*)d_in[7];
    const float* ln2_s   = (const float*)d_in[8];
    const float* ln2_b   = (const float*)d_in[9];
    const float* w1      = (const float*)d_in[10];
    const float* b1      = (const float*)d_in[11];
    const float* w2      = (const float*)d_in[12];
    const float* b2      = (const float*)d_in[13];
    const float* lnf_s   = (const float*)d_in[14];
    const float* lnf_b   = (const float*)d_in[15];

    float* h = (float*)d_out;
    ushortT* wsu = (ushortT*)d_ws;
    const size_t WPRE = 4718592;  // ushorts of tiled weights

    static const int cands[12] = {1, 2, 3, 4, 6, 8, 12, 16, 24, 32, 48, 96};
    int NC = 96;
    for (int i = 0; i < 12; ++i) {
        size_t tc = (size_t)T_TOK / cands[i];
        if (WPRE * 2 + tc * 3072 <= ws_size) { NC = cands[i]; break; }
    }
    const int TC = T_TOK / NC;
    const int BLC = BLROWS / NC;
    ushortT* xnC = wsu + WPRE;
    ushortT* big = xnC + (size_t)TC * 256;
    ushortT* oC  = big + (size_t)TC * 1024;

    wprep_kernel<<<576, 256, 0, stream>>>(qkv_w, proj_w, w1, w2, wsu);
    hipMemcpyAsync(h, x, (size_t)T_TOK * DMODEL * sizeof(float),
                   hipMemcpyDeviceToDevice, stream);

    dim3 blk(256);
    for (int d = 0; d < 6; ++d) {
        for (int c = 0; c < NC; ++c) {
            float* hc = h + (size_t)c * TC * DMODEL;
            ln_kernel<true><<<TC / 4, blk, 0, stream>>>(hc, xnC, ln1_s + d * 256, ln1_b + d * 256);
            gemm_bf16<0><<<dim3(TC / 128, 6), blk, 0, stream>>>(
                xnC, wsu + (size_t)d * 196608, qkv_b + d * 768, nullptr, big, 256, 768);
            attn_kernel<<<dim3(NSEQ / 64, BLC * 4), blk, 0, stream>>>(
                big, rel_tab + (size_t)d * 1023 * 4, oC);
            gemm_bf16<2><<<dim3(TC / 128, 2), blk, 0, stream>>>(
                oC, wsu + 1179648 + (size_t)d * 65536, proj_b + d * 256, hc, nullptr, 256, 256);
        }
        for (int c = 0; c < NC; ++c) {
            float* hc = h + (size_t)c * TC * DMODEL;
            ln_kernel<true><<<TC / 4, blk, 0, stream>>>(hc, xnC, ln2_s + d * 256, ln2_b + d * 256);
            gemm_bf16<1><<<dim3(TC / 128, 8), blk, 0, stream>>>(
                xnC, wsu + 1572864 + (size_t)d * 262144, b1 + d * 1024, nullptr, big, 256, 1024);
            gemm_bf16<2><<<dim3(TC / 128, 2), blk, 0, stream>>>(
                big, wsu + 3145728 + (size_t)d * 262144, b2 + d * 256, hc, nullptr, 1024, 256);
        }
    }
    ln_kernel<false><<<T_TOK / 4, blk, 0, stream>>>(h, h, lnf_s, lnf_b);
}

// Round 4
// 4123.165 us; speedup vs baseline: 2.1192x; 1.3093x over previous
//
#include <hip/hip_runtime.h>
#include <math.h>

// Problem constants (fixed by reference):
//   x: (8,12,512,256) fp32 -> tokens T = 8*12*512 = 49152, D = 256
//   DEPTH=6, HEADS=4, DH=64, N(seq)=512, batch-rows BL=96
#define T_TOK 49152
#define DMODEL 256
#define NSEQ 512
#define BLROWS 96

typedef unsigned short ushortT;
using frag_ab = __attribute__((ext_vector_type(8))) short;   // 8 bf16
using f32x4   = __attribute__((ext_vector_type(4))) float;   // 4 fp32 acc

__device__ __forceinline__ ushortT f2b(float f) {
    union { float f; unsigned int u; } v; v.f = f;
    unsigned int u = v.u;
    u += 0x7FFFu + ((u >> 16) & 1u);   // RNE
    return (ushortT)(u >> 16);
}
__device__ __forceinline__ float b2f(ushortT h) {
    union { unsigned int u; float f; } v; v.u = ((unsigned int)h) << 16;
    return v.f;
}

// ---------------------------------------------------------------------------
// Weight prep (once per launch): fp32 W[K][N] -> bf16 tiles [nb][ks][n:128][k:64]
// contiguous 8192-ushort tiles, ordered tt = nb*KS + ks.
// Layer bases (ushorts): qkv d*196608 | proj 1179648+d*65536 |
//                        w1 1572864+d*262144 | w2 3145728+d*262144 ; end 4718592
// ---------------------------------------------------------------------------
__global__ __launch_bounds__(256) void wprep_kernel(const float* __restrict__ qkv_w,
                                                    const float* __restrict__ proj_w,
                                                    const float* __restrict__ w1,
                                                    const float* __restrict__ w2,
                                                    ushortT* __restrict__ out) {
    __shared__ float Ls[64][132];
    int bid = blockIdx.x;
    int d = bid / 96, t = bid % 96;
    const float* src; int N, KS; size_t dbase; int tt;
    if (t < 24)      { src = qkv_w  + (size_t)d * 256 * 768;  N = 768;  KS = 4;  dbase = (size_t)d * 196608;            tt = t;      }
    else if (t < 32) { src = proj_w + (size_t)d * 256 * 256;  N = 256;  KS = 4;  dbase = 1179648 + (size_t)d * 65536;   tt = t - 24; }
    else if (t < 64) { src = w1     + (size_t)d * 256 * 1024; N = 1024; KS = 4;  dbase = 1572864 + (size_t)d * 262144;  tt = t - 32; }
    else             { src = w2     + (size_t)d * 1024 * 256; N = 256;  KS = 16; dbase = 3145728 + (size_t)d * 262144;  tt = t - 64; }
    int nb = tt / KS, ks = tt % KS;
    int k0 = ks * 64, n0 = nb * 128;
    int tid = threadIdx.x;
#pragma unroll
    for (int i = 0; i < 8; ++i) {
        int fidx = tid + i * 256;            // 0..2047 float4s of the 64x128 tile
        int kk = fidx >> 5, ng = fidx & 31;
        float4 v = *(const float4*)(src + (size_t)(k0 + kk) * N + n0 + ng * 4);
        *(float4*)&Ls[kk][ng * 4] = v;
    }
    __syncthreads();
    int n = tid & 127, kh = tid >> 7;
    ushortT* dst = out + dbase + (size_t)tt * 8192 + n * 64 + kh * 32;
    ushortT tmp[32];
#pragma unroll
    for (int j = 0; j < 32; ++j) tmp[j] = f2b(Ls[kh * 32 + j][n]);
#pragma unroll
    for (int u = 0; u < 4; ++u) *(uint4*)(dst + u * 8) = *(uint4*)(tmp + u * 8);
}

// ---------------------------------------------------------------------------
// LayerNorm: one wave per 256-float row. OB: bf16 out (for GEMM A), else fp32.
// ---------------------------------------------------------------------------
template <bool OB>
__global__ __launch_bounds__(256) void ln_kernel(const float* __restrict__ in,
                                                 void* __restrict__ out,
                                                 const float* __restrict__ s,
                                                 const float* __restrict__ b) {
    int wave = threadIdx.x >> 6;
    int lane = threadIdx.x & 63;
    size_t row = (size_t)blockIdx.x * 4 + wave;
    float4 v = reinterpret_cast<const float4*>(in + row * DMODEL)[lane];
    float sum = v.x + v.y + v.z + v.w;
    float ssq = v.x * v.x + v.y * v.y + v.z * v.z + v.w * v.w;
#pragma unroll
    for (int m = 1; m <= 32; m <<= 1) {
        sum += __shfl_xor(sum, m, 64);
        ssq += __shfl_xor(ssq, m, 64);
    }
    float mean = sum * (1.0f / 256.0f);
    float var = ssq * (1.0f / 256.0f) - mean * mean;
    float rstd = rsqrtf(var + 1e-5f);
    float4 sv = reinterpret_cast<const float4*>(s)[lane];
    float4 bv = reinterpret_cast<const float4*>(b)[lane];
    float o0 = (v.x - mean) * rstd * sv.x + bv.x;
    float o1 = (v.y - mean) * rstd * sv.y + bv.y;
    float o2 = (v.z - mean) * rstd * sv.z + bv.z;
    float o3 = (v.w - mean) * rstd * sv.w + bv.w;
    if (OB) {
        ushortT* po = (ushortT*)out + row * DMODEL + lane * 4;
        ushort4 ov; ov.x = f2b(o0); ov.y = f2b(o1); ov.z = f2b(o2); ov.w = f2b(o3);
        *(ushort4*)po = ov;
    } else {
        float4 ov; ov.x = o0; ov.y = o1; ov.z = o2; ov.w = o3;
        reinterpret_cast<float4*>((float*)out + row * DMODEL)[lane] = ov;
    }
}

// ---------------------------------------------------------------------------
// bf16 MFMA GEMM: C[M x N] = A[M x K](bf16) @ W(tiled bf16) + bias.
// 128x128 tile, BK=64, 4 waves in 2x2, each wave 64x64 (4x4 frags 16x16x32).
// LDS: Als/Bls [row:128][k:64] bf16, XOR-swizzled 16B units (u ^= row&7).
// EPI: 0 bias -> bf16 | 1 bias+gelu -> bf16 | 2 bias+residual(in-place f32 R)
// ---------------------------------------------------------------------------
template <int EPI>
__global__ __launch_bounds__(256) void gemm_bf16(const ushortT* __restrict__ A,
                                                 const ushortT* __restrict__ Wt,
                                                 const float* __restrict__ bias,
                                                 float* __restrict__ R,
                                                 ushortT* __restrict__ Cb,
                                                 int K, int N) {
    __shared__ ushortT Als[128 * 64];
    __shared__ ushortT Bls[128 * 64];
    const int m0 = blockIdx.x * 128, nb = blockIdx.y, n0 = nb * 128;
    const int tid = threadIdx.x, lane = tid & 63, wave = tid >> 6;
    const int wr = wave >> 1, wc = wave & 1;
    const int KS = K >> 6;

    // staging: thread t -> LDS row t>>1 (A: token row / B: out col), half t&1
    const int srow = tid >> 1, shalf = tid & 1;
    const ushortT* Abase = A + (size_t)(m0 + srow) * K + shalf * 32;
    const ushortT* Bbase = Wt + (size_t)nb * KS * 8192 + srow * 64 + shalf * 32;

    uint4 aq[4], bq[4];
    {
        const uint4* ap = (const uint4*)Abase;
        const uint4* bp = (const uint4*)Bbase;
#pragma unroll
        for (int u = 0; u < 4; ++u) { aq[u] = ap[u]; bq[u] = bp[u]; }
    }

    f32x4 acc[4][4];
#pragma unroll
    for (int i = 0; i < 4; ++i)
#pragma unroll
        for (int j = 0; j < 4; ++j) acc[i][j] = (f32x4)0.0f;

    for (int ks = 0; ks < KS; ++ks) {
        __syncthreads();
#pragma unroll
        for (int u = 0; u < 4; ++u) {
            int ku = shalf * 4 + u;
            int off = srow * 64 + ((ku ^ (srow & 7)) << 3);
            *(uint4*)&Als[off] = aq[u];
            *(uint4*)&Bls[off] = bq[u];
        }
        __syncthreads();
        if (ks + 1 < KS) {
            const uint4* ap = (const uint4*)(Abase + (ks + 1) * 64);
            const uint4* bp = (const uint4*)(Bbase + (size_t)(ks + 1) * 8192);
#pragma unroll
            for (int u = 0; u < 4; ++u) { aq[u] = ap[u]; bq[u] = bp[u]; }
        }
#pragma unroll
        for (int kst = 0; kst < 2; ++kst) {
            frag_ab af[4], bf[4];
            int ku = kst * 4 + (lane >> 4);
#pragma unroll
            for (int f = 0; f < 4; ++f) {
                int row = wr * 64 + f * 16 + (lane & 15);
                af[f] = *(frag_ab*)&Als[row * 64 + ((ku ^ (row & 7)) << 3)];
                int col = wc * 64 + f * 16 + (lane & 15);
                bf[f] = *(frag_ab*)&Bls[col * 64 + ((ku ^ (col & 7)) << 3)];
            }
#pragma unroll
            for (int mf = 0; mf < 4; ++mf)
#pragma unroll
                for (int nf = 0; nf < 4; ++nf)
                    acc[mf][nf] = __builtin_amdgcn_mfma_f32_16x16x32_bf16(
                        af[mf], bf[nf], acc[mf][nf], 0, 0, 0);
        }
    }

    // epilogue: lane holds C[row = .. + (lane>>4)*4 + r][col = .. + (lane&15)]
    const int cg = lane >> 4, cl = lane & 15;
#pragma unroll
    for (int nf = 0; nf < 4; ++nf) {
        int col = n0 + wc * 64 + nf * 16 + cl;
        float bv = bias[col];
#pragma unroll
        for (int mf = 0; mf < 4; ++mf) {
#pragma unroll
            for (int r = 0; r < 4; ++r) {
                int row = m0 + wr * 64 + mf * 16 + cg * 4 + r;
                float c = acc[mf][nf][r] + bv;
                if (EPI == 1) {
                    // gelu(tanh) == x * sigmoid(2*0.79788456*(x+0.044715x^3))
                    c = c / (1.0f + __expf(-1.5957691216f * (c + 0.044715f * c * c * c)));
                }
                if (EPI == 2) {
                    float* p = R + (size_t)row * N + col;
                    *p = *p + c;
                } else {
                    Cb[(size_t)row * N + col] = f2b(c);
                }
            }
        }
    }
}

// ---------------------------------------------------------------------------
// MFMA flash attention. Block = (pair = bl*4+head, 64-row q-block), 4 waves.
// Wave w owns q-rows i0 + w*16 .. +15 (Q A-frags in registers, loaded once).
// Per 64-key tile: stage K[j][d] (XOR-swizzled 16B units) and V transposed
// Vt[d][j] (stride 72, column-XOR swizzle); S = QK^T via 8 MFMA; online
// softmax in C-layout (row-reduce over shfl_xor 1,2,4,8); P -> bf16 pairs
// (shfl_xor(1), even lanes write words) into wave-private LDS rows; O += P@V
// via 8 MFMA. 2 barriers per tile. LDS 29 KB -> 5 blocks/CU.
// Grid (pairs, 8): q-blocks sharing K/V are gridDim.x apart -> same XCD.
// ---------------------------------------------------------------------------
__global__ __launch_bounds__(256) void attn_kernel(const ushortT* __restrict__ qkv,
                                                   const float* __restrict__ rel,
                                                   ushortT* __restrict__ o) {
    __shared__ ushortT Ks[64 * 64];   // [j][d] swizzled: unit d>>3 ^= (j&7)
    __shared__ ushortT Vt[64 * 72];   // [d][j] transposed: j ^= ((d>>3)<<3)
    __shared__ ushortT Ps[64 * 64];   // [i][j] swizzled like Ks (wave-private rows)
    __shared__ float   rl[1024];      // rel-pos bias for this head

    const int pair = blockIdx.x, qb = blockIdx.y;
    const int bl = pair >> 2, hh = pair & 3;
    const int tid = threadIdx.x;
    const int lane = tid & 63, w = tid >> 6;
    const int c15 = lane & 15, g = lane >> 4;
    const size_t base = (size_t)bl * NSEQ * 768;
    const int qoff = hh * 64, koff = 256 + hh * 64, voff = 512 + hh * 64;
    const int i0 = qb * 64;

    for (int i = tid; i < 1023; i += 256) rl[i] = rel[(size_t)i * 4 + hh];

    // Q fragments: lane holds Q[i0 + w*16 + c15][kst*32 + g*8 + jj]
    frag_ab qf[2];
    {
        const ushortT* qp = qkv + base + (size_t)(i0 + w * 16 + c15) * 768 + qoff + g * 8;
        qf[0] = *(const frag_ab*)(qp);
        qf[1] = *(const frag_ab*)(qp + 32);
    }

    float m_i[4], l_i[4];
    f32x4 oacc[4];
#pragma unroll
    for (int r = 0; r < 4; ++r) { m_i[r] = -1e30f; l_i[r] = 0.0f; }
#pragma unroll
    for (int nf = 0; nf < 4; ++nf) oacc[nf] = (f32x4)0.0f;

    const int irow = w * 16 + g * 4;          // C-layout row base (local)
    const int i7 = irow & 7;                  // (irow+r)&7 varies with r below

    for (int kt = 0; kt < 8; ++kt) {
        __syncthreads();  // prev tile's frag reads done before restage
#pragma unroll
        for (int it = 0; it < 2; ++it) {
            int idx = tid + it * 256;         // 0..511
            int j = idx >> 3, dg = idx & 7;
            const ushortT* kp = qkv + base + (size_t)(kt * 64 + j) * 768;
            uint4 kv4 = *(const uint4*)(kp + koff + dg * 8);
            *(uint4*)&Ks[j * 64 + ((dg ^ (j & 7)) << 3)] = kv4;
            uint4 vv4 = *(const uint4*)(kp + voff + dg * 8);
            ushortT tmp[8];
            *(uint4*)tmp = vv4;
            int jc = j ^ (dg << 3);
#pragma unroll
            for (int e = 0; e < 8; ++e) Vt[(dg * 8 + e) * 72 + jc] = tmp[e];
        }
        __syncthreads();

        // ---- S = Q @ K^T (8 MFMA) ----
        f32x4 sacc[4];
#pragma unroll
        for (int nf = 0; nf < 4; ++nf) sacc[nf] = (f32x4)0.0f;
#pragma unroll
        for (int kst = 0; kst < 2; ++kst) {
            int ku = kst * 4 + g;
#pragma unroll
            for (int nf = 0; nf < 4; ++nf) {
                int j = nf * 16 + c15;
                frag_ab kf = *(frag_ab*)&Ks[j * 64 + ((ku ^ (j & 7)) << 3)];
                sacc[nf] = __builtin_amdgcn_mfma_f32_16x16x32_bf16(qf[kst], kf, sacc[nf], 0, 0, 0);
            }
        }

        // ---- online softmax (C layout: row = irow + r, col = nf*16 + c15) ----
        float sv[4][4];     // [nf][r]
        const int rlb = i0 + irow - kt * 64 - c15 + 511;
#pragma unroll
        for (int nf = 0; nf < 4; ++nf)
#pragma unroll
            for (int r = 0; r < 4; ++r)
                sv[nf][r] = sacc[nf][r] * 0.125f + rl[rlb + r - nf * 16];

        float corr[4], psum[4];
        unsigned int words[4][4];
#pragma unroll
        for (int r = 0; r < 4; ++r) {
            float rmax = fmaxf(fmaxf(sv[0][r], sv[1][r]), fmaxf(sv[2][r], sv[3][r]));
#pragma unroll
            for (int m = 1; m <= 8; m <<= 1) rmax = fmaxf(rmax, __shfl_xor(rmax, m, 64));
            float mn = fmaxf(m_i[r], rmax);
            corr[r] = __expf(m_i[r] - mn);
            m_i[r] = mn;
            psum[r] = 0.0f;
        }
#pragma unroll
        for (int nf = 0; nf < 4; ++nf)
#pragma unroll
            for (int r = 0; r < 4; ++r) {
                float p = __expf(sv[nf][r] - m_i[r]);
                psum[r] += p;
                unsigned int own = (unsigned int)f2b(p);
                unsigned int other = (unsigned int)__shfl_xor((int)own, 1, 64);
                words[nf][r] = own | (other << 16);
            }
#pragma unroll
        for (int r = 0; r < 4; ++r) {
#pragma unroll
            for (int m = 1; m <= 8; m <<= 1) psum[r] += __shfl_xor(psum[r], m, 64);
            l_i[r] = l_i[r] * corr[r] + psum[r];
        }

        // P store: even lanes write (p[j2], p[j2+1]) words, wave-private rows
        if (!(lane & 1)) {
#pragma unroll
            for (int nf = 0; nf < 4; ++nf) {
                int j2 = nf * 16 + c15;
#pragma unroll
                for (int r = 0; r < 4; ++r) {
                    int i = irow + r;
                    *(unsigned int*)&Ps[i * 64 + ((((j2 >> 3) ^ (i & 7))) << 3) + (j2 & 7)] =
                        words[nf][r];
                }
            }
        }

        // rescale O by corr (rows match C layout: r indexes row irow+r)
#pragma unroll
        for (int nf = 0; nf < 4; ++nf)
#pragma unroll
            for (int r = 0; r < 4; ++r) oacc[nf][r] *= corr[r];

        // ---- O += P @ V (8 MFMA); P rows are wave-private (no barrier) ----
#pragma unroll
        for (int ks2 = 0; ks2 < 2; ++ks2) {
            int ip = w * 16 + c15;
            int jb = ks2 * 32 + g * 8;
            frag_ab pf = *(frag_ab*)&Ps[ip * 64 + (((jb >> 3) ^ (ip & 7)) << 3)];
#pragma unroll
            for (int nf = 0; nf < 4; ++nf) {
                int dh = nf * 16 + c15;
                int jv = jb ^ ((dh >> 3) << 3);
                frag_ab vf = *(frag_ab*)&Vt[dh * 72 + jv];
                oacc[nf] = __builtin_amdgcn_mfma_f32_16x16x32_bf16(pf, vf, oacc[nf], 0, 0, 0);
            }
        }
    }

    // epilogue: O /= l, pack pairs, even lanes write words
    float inv[4];
#pragma unroll
    for (int r = 0; r < 4; ++r) inv[r] = 1.0f / l_i[r];
#pragma unroll
    for (int nf = 0; nf < 4; ++nf)
#pragma unroll
        for (int r = 0; r < 4; ++r) {
            unsigned int own = (unsigned int)f2b(oacc[nf][r] * inv[r]);
            unsigned int other = (unsigned int)__shfl_xor((int)own, 1, 64);
            if (!(lane & 1)) {
                size_t trow = (size_t)bl * NSEQ + i0 + irow + r;
                *(unsigned int*)&o[trow * DMODEL + hh * 64 + nf * 16 + c15] = own | (other << 16);
            }
        }
}

// ---------------------------------------------------------------------------
// Orchestration. h (residual, fp32) lives in d_out. ws layout:
//   [0, 4718592) ushorts : pre-tiled bf16 weights (9.44 MB)
//   then per-chunk scratch (bf16): xnC TCx256 | big TCx1024 (qkv 768 / mid) |
//   oC TCx256  -> TC*3072 bytes. NC chosen from ws_size only (capture-stable).
// ---------------------------------------------------------------------------
extern "C" void kernel_launch(void* const* d_in, const int* in_sizes, int n_in,
                              void* d_out, int out_size, void* d_ws, size_t ws_size,
                              hipStream_t stream) {
    const float* x       = (const float*)d_in[0];
    const float* ln1_s   = (const float*)d_in[1];
    const float* ln1_b   = (const float*)d_in[2];
    const float* qkv_w   = (const float*)d_in[3];
    const float* qkv_b   = (const float*)d_in[4];
    const float* proj_w  = (const float*)d_in[5];
    const float* proj_b  = (const float*)d_in[6];
    const float* rel_tab = (const float*)d_in[7];
    const float* ln2_s   = (const float*)d_in[8];
    const float* ln2_b   = (const float*)d_in[9];
    const float* w1      = (const float*)d_in[10];
    const float* b1      = (const float*)d_in[11];
    const float* w2      = (const float*)d_in[12];
    const float* b2      = (const float*)d_in[13];
    const float* lnf_s   = (const float*)d_in[14];
    const float* lnf_b   = (const float*)d_in[15];

    float* h = (float*)d_out;
    ushortT* wsu = (ushortT*)d_ws;
    const size_t WPRE = 4718592;  // ushorts of tiled weights

    static const int cands[12] = {1, 2, 3, 4, 6, 8, 12, 16, 24, 32, 48, 96};
    int NC = 96;
    for (int i = 0; i < 12; ++i) {
        size_t tc = (size_t)T_TOK / cands[i];
        if (WPRE * 2 + tc * 3072 <= ws_size) { NC = cands[i]; break; }
    }
    const int TC = T_TOK / NC;
    const int BLC = BLROWS / NC;
    ushortT* xnC = wsu + WPRE;
    ushortT* big = xnC + (size_t)TC * 256;
    ushortT* oC  = big + (size_t)TC * 1024;

    wprep_kernel<<<576, 256, 0, stream>>>(qkv_w, proj_w, w1, w2, wsu);
    hipMemcpyAsync(h, x, (size_t)T_TOK * DMODEL * sizeof(float),
                   hipMemcpyDeviceToDevice, stream);

    dim3 blk(256);
    for (int d = 0; d < 6; ++d) {
        for (int c = 0; c < NC; ++c) {
            float* hc = h + (size_t)c * TC * DMODEL;
            ln_kernel<true><<<TC / 4, blk, 0, stream>>>(hc, xnC, ln1_s + d * 256, ln1_b + d * 256);
            gemm_bf16<0><<<dim3(TC / 128, 6), blk, 0, stream>>>(
                xnC, wsu + (size_t)d * 196608, qkv_b + d * 768, nullptr, big, 256, 768);
            attn_kernel<<<dim3(BLC * 4, NSEQ / 64), blk, 0, stream>>>(
                big, rel_tab + (size_t)d * 1023 * 4, oC);
            gemm_bf16<2><<<dim3(TC / 128, 2), blk, 0, stream>>>(
                oC, wsu + 1179648 + (size_t)d * 65536, proj_b + d * 256, hc, nullptr, 256, 256);
        }
        for (int c = 0; c < NC; ++c) {
            float* hc = h + (size_t)c * TC * DMODEL;
            ln_kernel<true><<<TC / 4, blk, 0, stream>>>(hc, xnC, ln2_s + d * 256, ln2_b + d * 256);
            gemm_bf16<1><<<dim3(TC / 128, 8), blk, 0, stream>>>(
                xnC, wsu + 1572864 + (size_t)d * 262144, b1 + d * 1024, nullptr, big, 256, 1024);
            gemm_bf16<2><<<dim3(TC / 128, 2), blk, 0, stream>>>(
                big, wsu + 3145728 + (size_t)d * 262144, b2 + d * 256, hc, nullptr, 1024, 256);
        }
    }
    ln_kernel<false><<<T_TOK / 4, blk, 0, stream>>>(h, h, lnf_s, lnf_b);
}

// Round 5
// 3981.351 us; speedup vs baseline: 2.1947x; 1.0356x over previous
//
#include <hip/hip_runtime.h>
#include <math.h>

// Problem constants (fixed by reference):
//   x: (8,12,512,256) fp32 -> tokens T = 8*12*512 = 49152, D = 256
//   DEPTH=6, HEADS=4, DH=64, N(seq)=512, batch-rows BL=96
#define T_TOK 49152
#define DMODEL 256
#define NSEQ 512
#define BLROWS 96

typedef unsigned short ushortT;
using frag_ab = __attribute__((ext_vector_type(8))) short;   // 8 bf16
using f32x4   = __attribute__((ext_vector_type(4))) float;   // 4 fp32 acc

__device__ __forceinline__ ushortT f2b(float f) {
    union { float f; unsigned int u; } v; v.f = f;
    unsigned int u = v.u;
    u += 0x7FFFu + ((u >> 16) & 1u);   // RNE
    return (ushortT)(u >> 16);
}
__device__ __forceinline__ float b2f(ushortT h) {
    union { unsigned int u; float f; } v; v.u = ((unsigned int)h) << 16;
    return v.f;
}

// ---------------------------------------------------------------------------
// Weight prep (once per launch): fp32 W[K][N] -> bf16 tiles [nb][ks][n:128][k:64]
// contiguous 8192-ushort tiles, ordered tt = nb*KS + ks.
// Layer bases (ushorts): qkv d*196608 | proj 1179648+d*65536 |
//                        w1 1572864+d*262144 | w2 3145728+d*262144 ; end 4718592
// ---------------------------------------------------------------------------
__global__ __launch_bounds__(256) void wprep_kernel(const float* __restrict__ qkv_w,
                                                    const float* __restrict__ proj_w,
                                                    const float* __restrict__ w1,
                                                    const float* __restrict__ w2,
                                                    ushortT* __restrict__ out) {
    __shared__ float Ls[64][132];
    int bid = blockIdx.x;
    int d = bid / 96, t = bid % 96;
    const float* src; int N, KS; size_t dbase; int tt;
    if (t < 24)      { src = qkv_w  + (size_t)d * 256 * 768;  N = 768;  KS = 4;  dbase = (size_t)d * 196608;            tt = t;      }
    else if (t < 32) { src = proj_w + (size_t)d * 256 * 256;  N = 256;  KS = 4;  dbase = 1179648 + (size_t)d * 65536;   tt = t - 24; }
    else if (t < 64) { src = w1     + (size_t)d * 256 * 1024; N = 1024; KS = 4;  dbase = 1572864 + (size_t)d * 262144;  tt = t - 32; }
    else             { src = w2     + (size_t)d * 1024 * 256; N = 256;  KS = 16; dbase = 3145728 + (size_t)d * 262144;  tt = t - 64; }
    int nb = tt / KS, ks = tt % KS;
    int k0 = ks * 64, n0 = nb * 128;
    int tid = threadIdx.x;
#pragma unroll
    for (int i = 0; i < 8; ++i) {
        int fidx = tid + i * 256;            // 0..2047 float4s of the 64x128 tile
        int kk = fidx >> 5, ng = fidx & 31;
        float4 v = *(const float4*)(src + (size_t)(k0 + kk) * N + n0 + ng * 4);
        *(float4*)&Ls[kk][ng * 4] = v;
    }
    __syncthreads();
    int n = tid & 127, kh = tid >> 7;
    ushortT* dst = out + dbase + (size_t)tt * 8192 + n * 64 + kh * 32;
    ushortT tmp[32];
#pragma unroll
    for (int j = 0; j < 32; ++j) tmp[j] = f2b(Ls[kh * 32 + j][n]);
#pragma unroll
    for (int u = 0; u < 4; ++u) *(uint4*)(dst + u * 8) = *(uint4*)(tmp + u * 8);
}

// ---------------------------------------------------------------------------
// LayerNorm: one wave per 256-float row. OB: bf16 out (for GEMM A), else fp32.
// ---------------------------------------------------------------------------
template <bool OB>
__global__ __launch_bounds__(256) void ln_kernel(const float* __restrict__ in,
                                                 void* __restrict__ out,
                                                 const float* __restrict__ s,
                                                 const float* __restrict__ b) {
    int wave = threadIdx.x >> 6;
    int lane = threadIdx.x & 63;
    size_t row = (size_t)blockIdx.x * 4 + wave;
    float4 v = reinterpret_cast<const float4*>(in + row * DMODEL)[lane];
    float sum = v.x + v.y + v.z + v.w;
    float ssq = v.x * v.x + v.y * v.y + v.z * v.z + v.w * v.w;
#pragma unroll
    for (int m = 1; m <= 32; m <<= 1) {
        sum += __shfl_xor(sum, m, 64);
        ssq += __shfl_xor(ssq, m, 64);
    }
    float mean = sum * (1.0f / 256.0f);
    float var = ssq * (1.0f / 256.0f) - mean * mean;
    float rstd = rsqrtf(var + 1e-5f);
    float4 sv = reinterpret_cast<const float4*>(s)[lane];
    float4 bv = reinterpret_cast<const float4*>(b)[lane];
    float o0 = (v.x - mean) * rstd * sv.x + bv.x;
    float o1 = (v.y - mean) * rstd * sv.y + bv.y;
    float o2 = (v.z - mean) * rstd * sv.z + bv.z;
    float o3 = (v.w - mean) * rstd * sv.w + bv.w;
    if (OB) {
        ushortT* po = (ushortT*)out + row * DMODEL + lane * 4;
        ushort4 ov; ov.x = f2b(o0); ov.y = f2b(o1); ov.z = f2b(o2); ov.w = f2b(o3);
        *(ushort4*)po = ov;
    } else {
        float4 ov; ov.x = o0; ov.y = o1; ov.z = o2; ov.w = o3;
        reinterpret_cast<float4*>((float*)out + row * DMODEL)[lane] = ov;
    }
}

// ---------------------------------------------------------------------------
// bf16 MFMA GEMM: C[M x N] = A[M x K](bf16) @ W(tiled bf16) + bias.
// 128x128 tile, BK=64, 4 waves in 2x2, each wave 64x64 (4x4 frags 16x16x32).
// LDS: Als/Bls [row:128][k:64] bf16, XOR-swizzled 16B units (u ^= row&7).
// Grid: (x = n-tiles, y = m-tiles) -> consecutive blocks share A panel (L3/L2).
// Epilogue routes C through the (now free) 32 KB staging LDS so global
// stores are uint4/float4 row-contiguous (256 B per 16 lanes), fixing the
// 5.7x write amplification seen with scalar stores.
// EPI: 0 bias -> bf16 | 1 bias+gelu -> bf16 | 2 bias+residual(in-place f32 R)
// ---------------------------------------------------------------------------
template <int EPI>
__global__ __launch_bounds__(256) void gemm_bf16(const ushortT* __restrict__ A,
                                                 const ushortT* __restrict__ Wt,
                                                 const float* __restrict__ bias,
                                                 float* __restrict__ R,
                                                 ushortT* __restrict__ Cb,
                                                 int K, int N) {
    __shared__ ushortT smem[16384];      // Als | Bls, reused as C-stage
    ushortT* Als = smem;                 // [128 rows][64 k] swizzled
    ushortT* Bls = smem + 8192;
    const int nb = blockIdx.x, n0 = nb * 128;
    const int m0 = blockIdx.y * 128;
    const int tid = threadIdx.x, lane = tid & 63, wave = tid >> 6;
    const int wr = wave >> 1, wc = wave & 1;
    const int KS = K >> 6;

    // staging: thread t -> LDS row t>>1 (A: token row / B: out col), half t&1
    const int srow = tid >> 1, shalf = tid & 1;
    const ushortT* Abase = A + (size_t)(m0 + srow) * K + shalf * 32;
    const ushortT* Bbase = Wt + (size_t)nb * KS * 8192 + srow * 64 + shalf * 32;

    uint4 aq[4], bq[4];
    {
        const uint4* ap = (const uint4*)Abase;
        const uint4* bp = (const uint4*)Bbase;
#pragma unroll
        for (int u = 0; u < 4; ++u) { aq[u] = ap[u]; bq[u] = bp[u]; }
    }

    f32x4 acc[4][4];
#pragma unroll
    for (int i = 0; i < 4; ++i)
#pragma unroll
        for (int j = 0; j < 4; ++j) acc[i][j] = (f32x4)0.0f;

    for (int ks = 0; ks < KS; ++ks) {
        __syncthreads();
#pragma unroll
        for (int u = 0; u < 4; ++u) {
            int ku = shalf * 4 + u;
            int off = srow * 64 + ((ku ^ (srow & 7)) << 3);
            *(uint4*)&Als[off] = aq[u];
            *(uint4*)&Bls[off] = bq[u];
        }
        __syncthreads();
        if (ks + 1 < KS) {
            const uint4* ap = (const uint4*)(Abase + (ks + 1) * 64);
            const uint4* bp = (const uint4*)(Bbase + (size_t)(ks + 1) * 8192);
#pragma unroll
            for (int u = 0; u < 4; ++u) { aq[u] = ap[u]; bq[u] = bp[u]; }
        }
#pragma unroll
        for (int kst = 0; kst < 2; ++kst) {
            frag_ab af[4], bf[4];
            int ku = kst * 4 + (lane >> 4);
#pragma unroll
            for (int f = 0; f < 4; ++f) {
                int row = wr * 64 + f * 16 + (lane & 15);
                af[f] = *(frag_ab*)&Als[row * 64 + ((ku ^ (row & 7)) << 3)];
                int col = wc * 64 + f * 16 + (lane & 15);
                bf[f] = *(frag_ab*)&Bls[col * 64 + ((ku ^ (col & 7)) << 3)];
            }
#pragma unroll
            for (int mf = 0; mf < 4; ++mf)
#pragma unroll
                for (int nf = 0; nf < 4; ++nf)
                    acc[mf][nf] = __builtin_amdgcn_mfma_f32_16x16x32_bf16(
                        af[mf], bf[nf], acc[mf][nf], 0, 0, 0);
        }
    }

    // ---- epilogue via LDS transpose -> wide coalesced stores ----
    const int cg = lane >> 4, cl = lane & 15;
    __syncthreads();   // MFMA fragment reads complete before LDS reuse
    if (EPI != 2) {
        ushortT* Cs = smem;   // [128][128] bf16, 16B-unit row-XOR swizzle
#pragma unroll
        for (int nf = 0; nf < 4; ++nf) {
            int col = wc * 64 + nf * 16 + cl;
            float bv = bias[n0 + col];
#pragma unroll
            for (int mf = 0; mf < 4; ++mf)
#pragma unroll
                for (int r = 0; r < 4; ++r) {
                    int row = wr * 64 + mf * 16 + cg * 4 + r;
                    float c = acc[mf][nf][r] + bv;
                    if (EPI == 1) {
                        // gelu(tanh) == x * sigmoid(1.5957691*(x+0.044715x^3))
                        c = c / (1.0f + __expf(-1.5957691216f * (c + 0.044715f * c * c * c)));
                    }
                    Cs[row * 128 + (((col >> 3) ^ (row & 7)) << 3) + (col & 7)] = f2b(c);
                }
        }
        __syncthreads();
#pragma unroll
        for (int it = 0; it < 8; ++it) {
            int idx = tid + it * 256;
            int row = idx >> 4, u = idx & 15;          // 16 lanes = 1 full row
            uint4 v = *(uint4*)&Cs[row * 128 + ((u ^ (row & 7)) << 3)];
            *(uint4*)&Cb[(size_t)(m0 + row) * N + n0 + u * 8] = v;
        }
    } else {
        float* Cf = (float*)smem;   // [64][128] fp32, float4-unit row-XOR swizzle
#pragma unroll
        for (int h = 0; h < 2; ++h) {
            if (wr == h) {
#pragma unroll
                for (int nf = 0; nf < 4; ++nf) {
                    int col = wc * 64 + nf * 16 + cl;
                    float bv = bias[n0 + col];
#pragma unroll
                    for (int mf = 0; mf < 4; ++mf)
#pragma unroll
                        for (int r = 0; r < 4; ++r) {
                            int rl = mf * 16 + cg * 4 + r;
                            Cf[rl * 128 + (((col >> 2) ^ (rl & 7)) << 2) + (col & 3)] =
                                acc[mf][nf][r] + bv;
                        }
                }
            }
            __syncthreads();
#pragma unroll
            for (int it = 0; it < 8; ++it) {
                int idx = tid + it * 256;
                int row2 = idx >> 5, u = idx & 31;     // 32 lanes = 1 full row
                float4 c4 = *(float4*)&Cf[row2 * 128 + ((u ^ (row2 & 7)) << 2)];
                float* rp = R + (size_t)(m0 + h * 64 + row2) * N + n0 + u * 4;
                float4 r4 = *(float4*)rp;
                r4.x += c4.x; r4.y += c4.y; r4.z += c4.z; r4.w += c4.w;
                *(float4*)rp = r4;
            }
            if (h == 0) __syncthreads();
        }
    }
}

// ---------------------------------------------------------------------------
// MFMA flash attention. Block = (pair = bl*4+head, 64-row q-block), 4 waves.
// Wave w owns q-rows i0 + w*16 .. +15 (Q A-frags in registers, loaded once).
// Per 64-key tile: stage K[j][d] (XOR-swizzled 16B units) and V transposed
// Vt[d][j] (stride 72, column-XOR swizzle); S = QK^T via 8 MFMA; online
// softmax in C-layout (row-reduce over shfl_xor 1,2,4,8); P -> bf16 pairs
// (shfl_xor(1), even lanes write words) into wave-private LDS rows; O += P@V
// via 8 MFMA. 2 barriers per tile. LDS 29 KB -> 5 blocks/CU.
// ---------------------------------------------------------------------------
__global__ __launch_bounds__(256) void attn_kernel(const ushortT* __restrict__ qkv,
                                                   const float* __restrict__ rel,
                                                   ushortT* __restrict__ o) {
    __shared__ ushortT Ks[64 * 64];   // [j][d] swizzled: unit d>>3 ^= (j&7)
    __shared__ ushortT Vt[64 * 72];   // [d][j] transposed: j ^= ((d>>3)<<3)
    __shared__ ushortT Ps[64 * 64];   // [i][j] swizzled like Ks (wave-private rows)
    __shared__ float   rl[1024];      // rel-pos bias for this head

    const int pair = blockIdx.x, qb = blockIdx.y;
    const int bl = pair >> 2, hh = pair & 3;
    const int tid = threadIdx.x;
    const int lane = tid & 63, w = tid >> 6;
    const int c15 = lane & 15, g = lane >> 4;
    const size_t base = (size_t)bl * NSEQ * 768;
    const int qoff = hh * 64, koff = 256 + hh * 64, voff = 512 + hh * 64;
    const int i0 = qb * 64;

    for (int i = tid; i < 1023; i += 256) rl[i] = rel[(size_t)i * 4 + hh];

    // Q fragments: lane holds Q[i0 + w*16 + c15][kst*32 + g*8 + jj]
    frag_ab qf[2];
    {
        const ushortT* qp = qkv + base + (size_t)(i0 + w * 16 + c15) * 768 + qoff + g * 8;
        qf[0] = *(const frag_ab*)(qp);
        qf[1] = *(const frag_ab*)(qp + 32);
    }

    float m_i[4], l_i[4];
    f32x4 oacc[4];
#pragma unroll
    for (int r = 0; r < 4; ++r) { m_i[r] = -1e30f; l_i[r] = 0.0f; }
#pragma unroll
    for (int nf = 0; nf < 4; ++nf) oacc[nf] = (f32x4)0.0f;

    const int irow = w * 16 + g * 4;          // C-layout row base (local)

    for (int kt = 0; kt < 8; ++kt) {
        __syncthreads();  // prev tile's frag reads done before restage
#pragma unroll
        for (int it = 0; it < 2; ++it) {
            int idx = tid + it * 256;         // 0..511
            int j = idx >> 3, dg = idx & 7;
            const ushortT* kp = qkv + base + (size_t)(kt * 64 + j) * 768;
            uint4 kv4 = *(const uint4*)(kp + koff + dg * 8);
            *(uint4*)&Ks[j * 64 + ((dg ^ (j & 7)) << 3)] = kv4;
            uint4 vv4 = *(const uint4*)(kp + voff + dg * 8);
            ushortT tmp[8];
            *(uint4*)tmp = vv4;
            int jc = j ^ (dg << 3);
#pragma unroll
            for (int e = 0; e < 8; ++e) Vt[(dg * 8 + e) * 72 + jc] = tmp[e];
        }
        __syncthreads();

        // ---- S = Q @ K^T (8 MFMA) ----
        f32x4 sacc[4];
#pragma unroll
        for (int nf = 0; nf < 4; ++nf) sacc[nf] = (f32x4)0.0f;
#pragma unroll
        for (int kst = 0; kst < 2; ++kst) {
            int ku = kst * 4 + g;
#pragma unroll
            for (int nf = 0; nf < 4; ++nf) {
                int j = nf * 16 + c15;
                frag_ab kf = *(frag_ab*)&Ks[j * 64 + ((ku ^ (j & 7)) << 3)];
                sacc[nf] = __builtin_amdgcn_mfma_f32_16x16x32_bf16(qf[kst], kf, sacc[nf], 0, 0, 0);
            }
        }

        // ---- online softmax (C layout: row = irow + r, col = nf*16 + c15) ----
        float sv[4][4];     // [nf][r]
        const int rlb = i0 + irow - kt * 64 - c15 + 511;
#pragma unroll
        for (int nf = 0; nf < 4; ++nf)
#pragma unroll
            for (int r = 0; r < 4; ++r)
                sv[nf][r] = sacc[nf][r] * 0.125f + rl[rlb + r - nf * 16];

        float corr[4], psum[4];
        unsigned int words[4][4];
#pragma unroll
        for (int r = 0; r < 4; ++r) {
            float rmax = fmaxf(fmaxf(sv[0][r], sv[1][r]), fmaxf(sv[2][r], sv[3][r]));
#pragma unroll
            for (int m = 1; m <= 8; m <<= 1) rmax = fmaxf(rmax, __shfl_xor(rmax, m, 64));
            float mn = fmaxf(m_i[r], rmax);
            corr[r] = __expf(m_i[r] - mn);
            m_i[r] = mn;
            psum[r] = 0.0f;
        }
#pragma unroll
        for (int nf = 0; nf < 4; ++nf)
#pragma unroll
            for (int r = 0; r < 4; ++r) {
                float p = __expf(sv[nf][r] - m_i[r]);
                psum[r] += p;
                unsigned int own = (unsigned int)f2b(p);
                unsigned int other = (unsigned int)__shfl_xor((int)own, 1, 64);
                words[nf][r] = own | (other << 16);
            }
#pragma unroll
        for (int r = 0; r < 4; ++r) {
#pragma unroll
            for (int m = 1; m <= 8; m <<= 1) psum[r] += __shfl_xor(psum[r], m, 64);
            l_i[r] = l_i[r] * corr[r] + psum[r];
        }

        // P store: even lanes write (p[j2], p[j2+1]) words, wave-private rows
        if (!(lane & 1)) {
#pragma unroll
            for (int nf = 0; nf < 4; ++nf) {
                int j2 = nf * 16 + c15;
#pragma unroll
                for (int r = 0; r < 4; ++r) {
                    int i = irow + r;
                    *(unsigned int*)&Ps[i * 64 + ((((j2 >> 3) ^ (i & 7))) << 3) + (j2 & 7)] =
                        words[nf][r];
                }
            }
        }

        // rescale O by corr (rows match C layout: r indexes row irow+r)
#pragma unroll
        for (int nf = 0; nf < 4; ++nf)
#pragma unroll
            for (int r = 0; r < 4; ++r) oacc[nf][r] *= corr[r];

        // ---- O += P @ V (8 MFMA); P rows are wave-private (no barrier) ----
#pragma unroll
        for (int ks2 = 0; ks2 < 2; ++ks2) {
            int ip = w * 16 + c15;
            int jb = ks2 * 32 + g * 8;
            frag_ab pf = *(frag_ab*)&Ps[ip * 64 + (((jb >> 3) ^ (ip & 7)) << 3)];
#pragma unroll
            for (int nf = 0; nf < 4; ++nf) {
                int dh = nf * 16 + c15;
                int jv = jb ^ ((dh >> 3) << 3);
                frag_ab vf = *(frag_ab*)&Vt[dh * 72 + jv];
                oacc[nf] = __builtin_amdgcn_mfma_f32_16x16x32_bf16(pf, vf, oacc[nf], 0, 0, 0);
            }
        }
    }

    // epilogue: O /= l, pack pairs, even lanes write words
    float inv[4];
#pragma unroll
    for (int r = 0; r < 4; ++r) inv[r] = 1.0f / l_i[r];
#pragma unroll
    for (int nf = 0; nf < 4; ++nf)
#pragma unroll
        for (int r = 0; r < 4; ++r) {
            unsigned int own = (unsigned int)f2b(oacc[nf][r] * inv[r]);
            unsigned int other = (unsigned int)__shfl_xor((int)own, 1, 64);
            if (!(lane & 1)) {
                size_t trow = (size_t)bl * NSEQ + i0 + irow + r;
                *(unsigned int*)&o[trow * DMODEL + hh * 64 + nf * 16 + c15] = own | (other << 16);
            }
        }
}

// ---------------------------------------------------------------------------
// Orchestration. h (residual, fp32) lives in d_out. ws layout:
//   [0, 4718592) ushorts : pre-tiled bf16 weights (9.44 MB)
//   then per-chunk scratch (bf16): xnC TCx256 | big TCx1024 (qkv 768 / mid) |
//   oC TCx256  -> TC*3072 bytes. NC chosen from ws_size only (capture-stable).
// ---------------------------------------------------------------------------
extern "C" void kernel_launch(void* const* d_in, const int* in_sizes, int n_in,
                              void* d_out, int out_size, void* d_ws, size_t ws_size,
                              hipStream_t stream) {
    const float* x       = (const float*)d_in[0];
    const float* ln1_s   = (const float*)d_in[1];
    const float* ln1_b   = (const float*)d_in[2];
    const float* qkv_w   = (const float*)d_in[3];
    const float* qkv_b   = (const float*)d_in[4];
    const float* proj_w  = (const float*)d_in[5];
    const float* proj_b  = (const float*)d_in[6];
    const float* rel_tab = (const float*)d_in[7];
    const float* ln2_s   = (const float*)d_in[8];
    const float* ln2_b   = (const float*)d_in[9];
    const float* w1      = (const float*)d_in[10];
    const float* b1      = (const float*)d_in[11];
    const float* w2      = (const float*)d_in[12];
    const float* b2      = (const float*)d_in[13];
    const float* lnf_s   = (const float*)d_in[14];
    const float* lnf_b   = (const float*)d_in[15];

    float* h = (float*)d_out;
    ushortT* wsu = (ushortT*)d_ws;
    const size_t WPRE = 4718592;  // ushorts of tiled weights

    static const int cands[12] = {1, 2, 3, 4, 6, 8, 12, 16, 24, 32, 48, 96};
    int NC = 96;
    for (int i = 0; i < 12; ++i) {
        size_t tc = (size_t)T_TOK / cands[i];
        if (WPRE * 2 + tc * 3072 <= ws_size) { NC = cands[i]; break; }
    }
    const int TC = T_TOK / NC;
    const int BLC = BLROWS / NC;
    ushortT* xnC = wsu + WPRE;
    ushortT* big = xnC + (size_t)TC * 256;
    ushortT* oC  = big + (size_t)TC * 1024;

    wprep_kernel<<<576, 256, 0, stream>>>(qkv_w, proj_w, w1, w2, wsu);
    hipMemcpyAsync(h, x, (size_t)T_TOK * DMODEL * sizeof(float),
                   hipMemcpyDeviceToDevice, stream);

    dim3 blk(256);
    for (int d = 0; d < 6; ++d) {
        for (int c = 0; c < NC; ++c) {
            float* hc = h + (size_t)c * TC * DMODEL;
            ln_kernel<true><<<TC / 4, blk, 0, stream>>>(hc, xnC, ln1_s + d * 256, ln1_b + d * 256);
            gemm_bf16<0><<<dim3(6, TC / 128), blk, 0, stream>>>(
                xnC, wsu + (size_t)d * 196608, qkv_b + d * 768, nullptr, big, 256, 768);
            attn_kernel<<<dim3(BLC * 4, NSEQ / 64), blk, 0, stream>>>(
                big, rel_tab + (size_t)d * 1023 * 4, oC);
            gemm_bf16<2><<<dim3(2, TC / 128), blk, 0, stream>>>(
                oC, wsu + 1179648 + (size_t)d * 65536, proj_b + d * 256, hc, nullptr, 256, 256);
        }
        for (int c = 0; c < NC; ++c) {
            float* hc = h + (size_t)c * TC * DMODEL;
            ln_kernel<true><<<TC / 4, blk, 0, stream>>>(hc, xnC, ln2_s + d * 256, ln2_b + d * 256);
            gemm_bf16<1><<<dim3(8, TC / 128), blk, 0, stream>>>(
                xnC, wsu + 1572864 + (size_t)d * 262144, b1 + d * 1024, nullptr, big, 256, 1024);
            gemm_bf16<2><<<dim3(2, TC / 128), blk, 0, stream>>>(
                big, wsu + 3145728 + (size_t)d * 262144, b2 + d * 256, hc, nullptr, 1024, 256);
        }
    }
    ln_kernel<false><<<T_TOK / 4, blk, 0, stream>>>(h, h, lnf_s, lnf_b);
}

// Round 7
// 2160.885 us; speedup vs baseline: 4.0437x; 1.8425x over previous
//
#include <hip/hip_runtime.h>
#include <math.h>

// Problem constants (fixed by reference):
//   x: (8,12,512,256) fp32 -> tokens T = 8*12*512 = 49152, D = 256
//   DEPTH=6, HEADS=4, DH=64, N(seq)=512, batch-rows BL=96
#define T_TOK 49152
#define DMODEL 256
#define NSEQ 512
#define BLROWS 96

typedef unsigned short ushortT;
using frag_ab = __attribute__((ext_vector_type(8))) short;   // 8 bf16
using f32x4   = __attribute__((ext_vector_type(4))) float;   // 4 fp32 acc

__device__ __forceinline__ ushortT f2b(float f) {
    union { float f; unsigned int u; } v; v.f = f;
    unsigned int u = v.u;
    u += 0x7FFFu + ((u >> 16) & 1u);   // RNE
    return (ushortT)(u >> 16);
}
__device__ __forceinline__ float b2f(ushortT h) {
    union { unsigned int u; float f; } v; v.u = ((unsigned int)h) << 16;
    return v.f;
}

// async global->LDS DMA, 16 B per lane; LDS dest = wave-uniform base + lane*16
__device__ __forceinline__ void gload_lds16(const ushortT* g, ushortT* l) {
    __builtin_amdgcn_global_load_lds(
        (const __attribute__((address_space(1))) unsigned int*)g,
        (__attribute__((address_space(3))) unsigned int*)l, 16, 0, 0);
}

// ---------------------------------------------------------------------------
// Weight prep (once per launch): fp32 W[K][N] -> bf16 tiles [nb][ks][n:128][k:64]
// contiguous 8192-ushort tiles, ordered tt = nb*KS + ks.
// Layer bases (ushorts): qkv d*196608 | proj 1179648+d*65536 |
//                        w1 1572864+d*262144 | w2 3145728+d*262144 ; end 4718592
// ---------------------------------------------------------------------------
__global__ __launch_bounds__(256) void wprep_kernel(const float* __restrict__ qkv_w,
                                                    const float* __restrict__ proj_w,
                                                    const float* __restrict__ w1,
                                                    const float* __restrict__ w2,
                                                    ushortT* __restrict__ out) {
    __shared__ float Ls[64][132];
    int bid = blockIdx.x;
    int d = bid / 96, t = bid % 96;
    const float* src; int N, KS; size_t dbase; int tt;
    if (t < 24)      { src = qkv_w  + (size_t)d * 256 * 768;  N = 768;  KS = 4;  dbase = (size_t)d * 196608;            tt = t;      }
    else if (t < 32) { src = proj_w + (size_t)d * 256 * 256;  N = 256;  KS = 4;  dbase = 1179648 + (size_t)d * 65536;   tt = t - 24; }
    else if (t < 64) { src = w1     + (size_t)d * 256 * 1024; N = 1024; KS = 4;  dbase = 1572864 + (size_t)d * 262144;  tt = t - 32; }
    else             { src = w2     + (size_t)d * 1024 * 256; N = 256;  KS = 16; dbase = 3145728 + (size_t)d * 262144;  tt = t - 64; }
    int nb = tt / KS, ks = tt % KS;
    int k0 = ks * 64, n0 = nb * 128;
    int tid = threadIdx.x;
#pragma unroll
    for (int i = 0; i < 8; ++i) {
        int fidx = tid + i * 256;            // 0..2047 float4s of the 64x128 tile
        int kk = fidx >> 5, ng = fidx & 31;
        float4 v = *(const float4*)(src + (size_t)(k0 + kk) * N + n0 + ng * 4);
        *(float4*)&Ls[kk][ng * 4] = v;
    }
    __syncthreads();
    int n = tid & 127, kh = tid >> 7;
    ushortT* dst = out + dbase + (size_t)tt * 8192 + n * 64 + kh * 32;
    ushortT tmp[32];
#pragma unroll
    for (int j = 0; j < 32; ++j) tmp[j] = f2b(Ls[kh * 32 + j][n]);
#pragma unroll
    for (int u = 0; u < 4; ++u) *(uint4*)(dst + u * 8) = *(uint4*)(tmp + u * 8);
}

// ---------------------------------------------------------------------------
// LayerNorm: one wave per 256-float row. OB: bf16 out (for GEMM A), else fp32.
// ---------------------------------------------------------------------------
template <bool OB>
__global__ __launch_bounds__(256) void ln_kernel(const float* __restrict__ in,
                                                 void* __restrict__ out,
                                                 const float* __restrict__ s,
                                                 const float* __restrict__ b) {
    int wave = threadIdx.x >> 6;
    int lane = threadIdx.x & 63;
    size_t row = (size_t)blockIdx.x * 4 + wave;
    float4 v = reinterpret_cast<const float4*>(in + row * DMODEL)[lane];
    float sum = v.x + v.y + v.z + v.w;
    float ssq = v.x * v.x + v.y * v.y + v.z * v.z + v.w * v.w;
#pragma unroll
    for (int m = 1; m <= 32; m <<= 1) {
        sum += __shfl_xor(sum, m, 64);
        ssq += __shfl_xor(ssq, m, 64);
    }
    float mean = sum * (1.0f / 256.0f);
    float var = ssq * (1.0f / 256.0f) - mean * mean;
    float rstd = rsqrtf(var + 1e-5f);
    float4 sv = reinterpret_cast<const float4*>(s)[lane];
    float4 bv = reinterpret_cast<const float4*>(b)[lane];
    float o0 = (v.x - mean) * rstd * sv.x + bv.x;
    float o1 = (v.y - mean) * rstd * sv.y + bv.y;
    float o2 = (v.z - mean) * rstd * sv.z + bv.z;
    float o3 = (v.w - mean) * rstd * sv.w + bv.w;
    if (OB) {
        ushortT* po = (ushortT*)out + row * DMODEL + lane * 4;
        ushort4 ov; ov.x = f2b(o0); ov.y = f2b(o1); ov.z = f2b(o2); ov.w = f2b(o3);
        *(ushort4*)po = ov;
    } else {
        float4 ov; ov.x = o0; ov.y = o1; ov.z = o2; ov.w = o3;
        reinterpret_cast<float4*>((float*)out + row * DMODEL)[lane] = ov;
    }
}

// ---------------------------------------------------------------------------
// bf16 MFMA GEMM: C[M x N] = A[M x K](bf16) @ W(tiled bf16) + bias.
// 128x128 tile, BK=64, 4 waves (2x2), 4x4 16x16x32 frags per wave.
// K-loop: double-buffered LDS, staged via global_load_lds (16 B/lane DMA),
// ONE barrier per K-step; STAGE(t+1) issues before compute(t) so the DMA
// flies under the MFMAs (T3-minimum schedule).
// Swizzle: LDS dest linear; XOR applied on the per-lane GLOBAL source column
// (unit ^= row&7) and on reads -> conflict-free b128 frag reads (rule #21).
// Epilogue routes C through LDS so global stores are uint4/float4
// row-contiguous (256 B per 16 lanes).
// EPI: 0 bias -> bf16 | 1 bias+gelu -> bf16 | 2 bias+residual(in-place f32 R)
// ---------------------------------------------------------------------------
template <int EPI>
__global__ __launch_bounds__(256) void gemm_bf16(const ushortT* __restrict__ A,
                                                 const ushortT* __restrict__ Wt,
                                                 const float* __restrict__ bias,
                                                 float* __restrict__ R,
                                                 ushortT* __restrict__ Cb,
                                                 int K, int N) {
    __shared__ ushortT smem[32768];      // 2 x (A 8192 | B 8192), reused as C-stage
    const int nb = blockIdx.x, n0 = nb * 128;
    const int m0 = blockIdx.y * 128;
    const int tid = threadIdx.x, lane = tid & 63, wave = tid >> 6;
    const int wr = wave >> 1, wc = wave & 1;
    const int KS = K >> 6;
    const size_t wtile = (size_t)nb * KS * 8192;

    const int rA = lane >> 3;                 // 0..7 (row within 8-row DMA group)
    const int colsw = (lane & 7) ^ rA;        // pre-swizzled source 16B unit

    // stage K-step kt into buffer buf; each wave: 4x A-DMA + 4x B-DMA (1 KB each)
    auto STAGE = [&](int buf, int kt) {
        ushortT* Ad = smem + buf * 16384;
        ushortT* Bd = Ad + 8192;
#pragma unroll
        for (int c2 = 0; c2 < 4; ++c2) {
            int rb = wave * 32 + c2 * 8;      // LDS row base (wave-uniform)
            int row = rb + rA;                // per-lane row
            gload_lds16(A + (size_t)(m0 + row) * K + kt * 64 + colsw * 8,
                        Ad + rb * 64);
            gload_lds16(Wt + wtile + (size_t)kt * 8192 + row * 64 + colsw * 8,
                        Bd + rb * 64);
        }
    };

    f32x4 acc[4][4];
#pragma unroll
    for (int i = 0; i < 4; ++i)
#pragma unroll
        for (int j = 0; j < 4; ++j) acc[i][j] = (f32x4)0.0f;

    STAGE(0, 0);
    __syncthreads();                          // drains vmcnt -> buf0 ready
    int cur = 0;
    for (int kt = 0; kt < KS; ++kt) {
        if (kt + 1 < KS) STAGE(cur ^ 1, kt + 1);   // DMA flies under MFMAs
        const ushortT* Ab = smem + cur * 16384;
        const ushortT* Bb = Ab + 8192;
#pragma unroll
        for (int kst = 0; kst < 2; ++kst) {
            frag_ab af[4], bf4[4];
            int ku = kst * 4 + (lane >> 4);
#pragma unroll
            for (int f = 0; f < 4; ++f) {
                int row = wr * 64 + f * 16 + (lane & 15);
                af[f] = *(const frag_ab*)&Ab[row * 64 + ((ku ^ (row & 7)) << 3)];
                int col = wc * 64 + f * 16 + (lane & 15);
                bf4[f] = *(const frag_ab*)&Bb[col * 64 + ((ku ^ (col & 7)) << 3)];
            }
#pragma unroll
            for (int mf = 0; mf < 4; ++mf)
#pragma unroll
                for (int nf = 0; nf < 4; ++nf)
                    acc[mf][nf] = __builtin_amdgcn_mfma_f32_16x16x32_bf16(
                        af[mf], bf4[nf], acc[mf][nf], 0, 0, 0);
        }
        __syncthreads();   // drains this step's DMA; protects buf reuse
        cur ^= 1;
    }

    // ---- epilogue via LDS transpose -> wide coalesced stores ----
    const int cg = lane >> 4, cl = lane & 15;
    if (EPI != 2) {
        ushortT* Cs = smem;   // [128][128] bf16, 16B-unit row-XOR swizzle
#pragma unroll
        for (int nf = 0; nf < 4; ++nf) {
            int col = wc * 64 + nf * 16 + cl;
            float bv = bias[n0 + col];
#pragma unroll
            for (int mf = 0; mf < 4; ++mf)
#pragma unroll
                for (int r = 0; r < 4; ++r) {
                    int row = wr * 64 + mf * 16 + cg * 4 + r;
                    float c = acc[mf][nf][r] + bv;
                    if (EPI == 1) {
                        // gelu(tanh) == x * sigmoid(1.5957691*(x+0.044715x^3))
                        c = c / (1.0f + __expf(-1.5957691216f * (c + 0.044715f * c * c * c)));
                    }
                    Cs[row * 128 + (((col >> 3) ^ (row & 7)) << 3) + (col & 7)] = f2b(c);
                }
        }
        __syncthreads();
#pragma unroll
        for (int it = 0; it < 8; ++it) {
            int idx = tid + it * 256;
            int row = idx >> 4, u = idx & 15;          // 16 lanes = 1 full row
            uint4 v = *(uint4*)&Cs[row * 128 + ((u ^ (row & 7)) << 3)];
            *(uint4*)&Cb[(size_t)(m0 + row) * N + n0 + u * 8] = v;
        }
    } else {
        float* Cf = (float*)smem;   // [64][128] fp32, float4-unit row-XOR swizzle
#pragma unroll
        for (int h = 0; h < 2; ++h) {
            if (wr == h) {
#pragma unroll
                for (int nf = 0; nf < 4; ++nf) {
                    int col = wc * 64 + nf * 16 + cl;
                    float bv = bias[n0 + col];
#pragma unroll
                    for (int mf = 0; mf < 4; ++mf)
#pragma unroll
                        for (int r = 0; r < 4; ++r) {
                            int rl = mf * 16 + cg * 4 + r;
                            Cf[rl * 128 + (((col >> 2) ^ (rl & 7)) << 2) + (col & 3)] =
                                acc[mf][nf][r] + bv;
                        }
                }
            }
            __syncthreads();
#pragma unroll
            for (int it = 0; it < 8; ++it) {
                int idx = tid + it * 256;
                int row2 = idx >> 5, u = idx & 31;     // 32 lanes = 1 full row
                float4 c4 = *(float4*)&Cf[row2 * 128 + ((u ^ (row2 & 7)) << 2)];
                float* rp = R + (size_t)(m0 + h * 64 + row2) * N + n0 + u * 4;
                float4 r4 = *(float4*)rp;
                r4.x += c4.x; r4.y += c4.y; r4.z += c4.z; r4.w += c4.w;
                *(float4*)rp = r4;
            }
            if (h == 0) __syncthreads();
        }
    }
}

// ---------------------------------------------------------------------------
// MFMA flash attention. Block = (pair = bl*4+head, 64-row q-block), 4 waves.
// Wave w owns q-rows i0 + w*16 .. +15 (Q A-frags in registers, loaded once).
// Per 64-key tile: stage K[j][d] (XOR-swizzled 16B units) and V transposed
// Vt[d][j] (stride 72, column-XOR swizzle); S = QK^T via 8 MFMA; online
// softmax in C-layout (row-reduce over shfl_xor 1,2,4,8); P -> bf16 pairs
// (shfl_xor(1), even lanes write words) into wave-private LDS rows; O += P@V
// via 8 MFMA. 2 barriers per tile. LDS 29 KB -> 5 blocks/CU.
// ---------------------------------------------------------------------------
__global__ __launch_bounds__(256) void attn_kernel(const ushortT* __restrict__ qkv,
                                                   const float* __restrict__ rel,
                                                   ushortT* __restrict__ o) {
    __shared__ ushortT Ks[64 * 64];   // [j][d] swizzled: unit d>>3 ^= (j&7)
    __shared__ ushortT Vt[64 * 72];   // [d][j] transposed: j ^= ((d>>3)<<3)
    __shared__ ushortT Ps[64 * 64];   // [i][j] swizzled like Ks (wave-private rows)
    __shared__ float   rl[1024];      // rel-pos bias for this head

    const int pair = blockIdx.x, qb = blockIdx.y;
    const int bl = pair >> 2, hh = pair & 3;
    const int tid = threadIdx.x;
    const int lane = tid & 63, w = tid >> 6;
    const int c15 = lane & 15, g = lane >> 4;
    const size_t base = (size_t)bl * NSEQ * 768;
    const int qoff = hh * 64, koff = 256 + hh * 64, voff = 512 + hh * 64;
    const int i0 = qb * 64;

    for (int i = tid; i < 1023; i += 256) rl[i] = rel[(size_t)i * 4 + hh];

    // Q fragments: lane holds Q[i0 + w*16 + c15][kst*32 + g*8 + jj]
    frag_ab qf[2];
    {
        const ushortT* qp = qkv + base + (size_t)(i0 + w * 16 + c15) * 768 + qoff + g * 8;
        qf[0] = *(const frag_ab*)(qp);
        qf[1] = *(const frag_ab*)(qp + 32);
    }

    float m_i[4], l_i[4];
    f32x4 oacc[4];
#pragma unroll
    for (int r = 0; r < 4; ++r) { m_i[r] = -1e30f; l_i[r] = 0.0f; }
#pragma unroll
    for (int nf = 0; nf < 4; ++nf) oacc[nf] = (f32x4)0.0f;

    const int irow = w * 16 + g * 4;          // C-layout row base (local)

    for (int kt = 0; kt < 8; ++kt) {
        __syncthreads();  // prev tile's frag reads done before restage
#pragma unroll
        for (int it = 0; it < 2; ++it) {
            int idx = tid + it * 256;         // 0..511
            int j = idx >> 3, dg = idx & 7;
            const ushortT* kp = qkv + base + (size_t)(kt * 64 + j) * 768;
            uint4 kv4 = *(const uint4*)(kp + koff + dg * 8);
            *(uint4*)&Ks[j * 64 + ((dg ^ (j & 7)) << 3)] = kv4;
            uint4 vv4 = *(const uint4*)(kp + voff + dg * 8);
            ushortT tmp[8];
            *(uint4*)tmp = vv4;
            int jc = j ^ (dg << 3);
#pragma unroll
            for (int e = 0; e < 8; ++e) Vt[(dg * 8 + e) * 72 + jc] = tmp[e];
        }
        __syncthreads();

        // ---- S = Q @ K^T (8 MFMA) ----
        f32x4 sacc[4];
#pragma unroll
        for (int nf = 0; nf < 4; ++nf) sacc[nf] = (f32x4)0.0f;
#pragma unroll
        for (int kst = 0; kst < 2; ++kst) {
            int ku = kst * 4 + g;
#pragma unroll
            for (int nf = 0; nf < 4; ++nf) {
                int j = nf * 16 + c15;
                frag_ab kf = *(frag_ab*)&Ks[j * 64 + ((ku ^ (j & 7)) << 3)];
                sacc[nf] = __builtin_amdgcn_mfma_f32_16x16x32_bf16(qf[kst], kf, sacc[nf], 0, 0, 0);
            }
        }

        // ---- online softmax (C layout: row = irow + r, col = nf*16 + c15) ----
        float sv[4][4];     // [nf][r]
        const int rlb = i0 + irow - kt * 64 - c15 + 511;
#pragma unroll
        for (int nf = 0; nf < 4; ++nf)
#pragma unroll
            for (int r = 0; r < 4; ++r)
                sv[nf][r] = sacc[nf][r] * 0.125f + rl[rlb + r - nf * 16];

        float corr[4], psum[4];
        unsigned int words[4][4];
#pragma unroll
        for (int r = 0; r < 4; ++r) {
            float rmax = fmaxf(fmaxf(sv[0][r], sv[1][r]), fmaxf(sv[2][r], sv[3][r]));
#pragma unroll
            for (int m = 1; m <= 8; m <<= 1) rmax = fmaxf(rmax, __shfl_xor(rmax, m, 64));
            float mn = fmaxf(m_i[r], rmax);
            corr[r] = __expf(m_i[r] - mn);
            m_i[r] = mn;
            psum[r] = 0.0f;
        }
#pragma unroll
        for (int nf = 0; nf < 4; ++nf)
#pragma unroll
            for (int r = 0; r < 4; ++r) {
                float p = __expf(sv[nf][r] - m_i[r]);
                psum[r] += p;
                unsigned int own = (unsigned int)f2b(p);
                unsigned int other = (unsigned int)__shfl_xor((int)own, 1, 64);
                words[nf][r] = own | (other << 16);
            }
#pragma unroll
        for (int r = 0; r < 4; ++r) {
#pragma unroll
            for (int m = 1; m <= 8; m <<= 1) psum[r] += __shfl_xor(psum[r], m, 64);
            l_i[r] = l_i[r] * corr[r] + psum[r];
        }

        // P store: even lanes write (p[j2], p[j2+1]) words, wave-private rows
        if (!(lane & 1)) {
#pragma unroll
            for (int nf = 0; nf < 4; ++nf) {
                int j2 = nf * 16 + c15;
#pragma unroll
                for (int r = 0; r < 4; ++r) {
                    int i = irow + r;
                    *(unsigned int*)&Ps[i * 64 + ((((j2 >> 3) ^ (i & 7))) << 3) + (j2 & 7)] =
                        words[nf][r];
                }
            }
        }

        // rescale O by corr (rows match C layout: r indexes row irow+r)
#pragma unroll
        for (int nf = 0; nf < 4; ++nf)
#pragma unroll
            for (int r = 0; r < 4; ++r) oacc[nf][r] *= corr[r];

        // ---- O += P @ V (8 MFMA); P rows are wave-private (no barrier) ----
#pragma unroll
        for (int ks2 = 0; ks2 < 2; ++ks2) {
            int ip = w * 16 + c15;
            int jb = ks2 * 32 + g * 8;
            frag_ab pf = *(frag_ab*)&Ps[ip * 64 + (((jb >> 3) ^ (ip & 7)) << 3)];
#pragma unroll
            for (int nf = 0; nf < 4; ++nf) {
                int dh = nf * 16 + c15;
                int jv = jb ^ ((dh >> 3) << 3);
                frag_ab vf = *(frag_ab*)&Vt[dh * 72 + jv];
                oacc[nf] = __builtin_amdgcn_mfma_f32_16x16x32_bf16(pf, vf, oacc[nf], 0, 0, 0);
            }
        }
    }

    // epilogue: O /= l, pack pairs, even lanes write words
    float inv[4];
#pragma unroll
    for (int r = 0; r < 4; ++r) inv[r] = 1.0f / l_i[r];
#pragma unroll
    for (int nf = 0; nf < 4; ++nf)
#pragma unroll
        for (int r = 0; r < 4; ++r) {
            unsigned int own = (unsigned int)f2b(oacc[nf][r] * inv[r]);
            unsigned int other = (unsigned int)__shfl_xor((int)own, 1, 64);
            if (!(lane & 1)) {
                size_t trow = (size_t)bl * NSEQ + i0 + irow + r;
                *(unsigned int*)&o[trow * DMODEL + hh * 64 + nf * 16 + c15] = own | (other << 16);
            }
        }
}

// ---------------------------------------------------------------------------
// Orchestration. h (residual, fp32) lives in d_out. ws layout:
//   [0, 4718592) ushorts : pre-tiled bf16 weights (9.44 MB)
//   then per-chunk scratch (bf16): xnC TCx256 | big TCx1024 (qkv 768 / mid) |
//   oC TCx256  -> TC*3072 bytes. NC chosen from ws_size only (capture-stable).
// ---------------------------------------------------------------------------
extern "C" void kernel_launch(void* const* d_in, const int* in_sizes, int n_in,
                              void* d_out, int out_size, void* d_ws, size_t ws_size,
                              hipStream_t stream) {
    const float* x       = (const float*)d_in[0];
    const float* ln1_s   = (const float*)d_in[1];
    const float* ln1_b   = (const float*)d_in[2];
    const float* qkv_w   = (const float*)d_in[3];
    const float* qkv_b   = (const float*)d_in[4];
    const float* proj_w  = (const float*)d_in[5];
    const float* proj_b  = (const float*)d_in[6];
    const float* rel_tab = (const float*)d_in[7];
    const float* ln2_s   = (const float*)d_in[8];
    const float* ln2_b   = (const float*)d_in[9];
    const float* w1      = (const float*)d_in[10];
    const float* b1      = (const float*)d_in[11];
    const float* w2      = (const float*)d_in[12];
    const float* b2      = (const float*)d_in[13];
    const float* lnf_s   = (const float*)d_in[14];
    const float* lnf_b   = (const float*)d_in[15];

    float* h = (float*)d_out;
    ushortT* wsu = (ushortT*)d_ws;
    const size_t WPRE = 4718592;  // ushorts of tiled weights

    static const int cands[12] = {1, 2, 3, 4, 6, 8, 12, 16, 24, 32, 48, 96};
    int NC = 96;
    for (int i = 0; i < 12; ++i) {
        size_t tc = (size_t)T_TOK / cands[i];
        if (WPRE * 2 + tc * 3072 <= ws_size) { NC = cands[i]; break; }
    }
    const int TC = T_TOK / NC;
    const int BLC = BLROWS / NC;
    ushortT* xnC = wsu + WPRE;
    ushortT* big = xnC + (size_t)TC * 256;
    ushortT* oC  = big + (size_t)TC * 1024;

    wprep_kernel<<<576, 256, 0, stream>>>(qkv_w, proj_w, w1, w2, wsu);
    hipMemcpyAsync(h, x, (size_t)T_TOK * DMODEL * sizeof(float),
                   hipMemcpyDeviceToDevice, stream);

    dim3 blk(256);
    for (int d = 0; d < 6; ++d) {
        for (int c = 0; c < NC; ++c) {
            float* hc = h + (size_t)c * TC * DMODEL;
            ln_kernel<true><<<TC / 4, blk, 0, stream>>>(hc, xnC, ln1_s + d * 256, ln1_b + d * 256);
            gemm_bf16<0><<<dim3(6, TC / 128), blk, 0, stream>>>(
                xnC, wsu + (size_t)d * 196608, qkv_b + d * 768, nullptr, big, 256, 768);
            attn_kernel<<<dim3(BLC * 4, NSEQ / 64), blk, 0, stream>>>(
                big, rel_tab + (size_t)d * 1023 * 4, oC);
            gemm_bf16<2><<<dim3(2, TC / 128), blk, 0, stream>>>(
                oC, wsu + 1179648 + (size_t)d * 65536, proj_b + d * 256, hc, nullptr, 256, 256);
        }
        for (int c = 0; c < NC; ++c) {
            float* hc = h + (size_t)c * TC * DMODEL;
            ln_kernel<true><<<TC / 4, blk, 0, stream>>>(hc, xnC, ln2_s + d * 256, ln2_b + d * 256);
            gemm_bf16<1><<<dim3(8, TC / 128), blk, 0, stream>>>(
                xnC, wsu + 1572864 + (size_t)d * 262144, b1 + d * 1024, nullptr, big, 256, 1024);
            gemm_bf16<2><<<dim3(2, TC / 128), blk, 0, stream>>>(
                big, wsu + 3145728 + (size_t)d * 262144, b2 + d * 256, hc, nullptr, 1024, 256);
        }
    }
    ln_kernel<false><<<T_TOK / 4, blk, 0, stream>>>(h, h, lnf_s, lnf_b);
}

// Round 8
// 2051.402 us; speedup vs baseline: 4.2595x; 1.0534x over previous
//
#include <hip/hip_runtime.h>
#include <math.h>

// Problem constants (fixed by reference):
//   x: (8,12,512,256) fp32 -> tokens T = 8*12*512 = 49152, D = 256
//   DEPTH=6, HEADS=4, DH=64, N(seq)=512, batch-rows BL=96
#define T_TOK 49152
#define DMODEL 256
#define NSEQ 512
#define BLROWS 96
#define LOG2E 1.4426950408889634f

typedef unsigned short ushortT;
using frag_ab = __attribute__((ext_vector_type(8))) short;   // 8 bf16
using f32x4   = __attribute__((ext_vector_type(4))) float;   // 4 fp32 acc

__device__ __forceinline__ ushortT f2b(float f) {
    union { float f; unsigned int u; } v; v.f = f;
    unsigned int u = v.u;
    u += 0x7FFFu + ((u >> 16) & 1u);   // RNE
    return (ushortT)(u >> 16);
}
__device__ __forceinline__ float b2f(ushortT h) {
    union { unsigned int u; float f; } v; v.u = ((unsigned int)h) << 16;
    return v.f;
}

#if __has_builtin(__builtin_amdgcn_exp2f)
#define FEXP2(x) __builtin_amdgcn_exp2f(x)
#else
#define FEXP2(x) __expf((x) * 0.6931471805599453f)
#endif

// pack two f32 -> one dword of 2 bf16 (RNE) in a single VALU op
__device__ __forceinline__ unsigned int cvtpk_bf16(float lo, float hi) {
    unsigned int r;
    asm("v_cvt_pk_bf16_f32 %0, %1, %2" : "=v"(r) : "v"(lo), "v"(hi));
    return r;
}

// async global->LDS DMA, 16 B per lane; LDS dest = wave-uniform base + lane*16
__device__ __forceinline__ void gload_lds16(const ushortT* g, ushortT* l) {
    __builtin_amdgcn_global_load_lds(
        (const __attribute__((address_space(1))) unsigned int*)g,
        (__attribute__((address_space(3))) unsigned int*)l, 16, 0, 0);
}

// ---------------------------------------------------------------------------
// Weight prep (once per launch): fp32 W[K][N] -> bf16 tiles [nb][ks][n:128][k:64]
// contiguous 8192-ushort tiles, ordered tt = nb*KS + ks.
// Layer bases (ushorts): qkv d*196608 | proj 1179648+d*65536 |
//                        w1 1572864+d*262144 | w2 3145728+d*262144 ; end 4718592
// ---------------------------------------------------------------------------
__global__ __launch_bounds__(256) void wprep_kernel(const float* __restrict__ qkv_w,
                                                    const float* __restrict__ proj_w,
                                                    const float* __restrict__ w1,
                                                    const float* __restrict__ w2,
                                                    ushortT* __restrict__ out) {
    __shared__ float Ls[64][132];
    int bid = blockIdx.x;
    int d = bid / 96, t = bid % 96;
    const float* src; int N, KS; size_t dbase; int tt;
    if (t < 24)      { src = qkv_w  + (size_t)d * 256 * 768;  N = 768;  KS = 4;  dbase = (size_t)d * 196608;            tt = t;      }
    else if (t < 32) { src = proj_w + (size_t)d * 256 * 256;  N = 256;  KS = 4;  dbase = 1179648 + (size_t)d * 65536;   tt = t - 24; }
    else if (t < 64) { src = w1     + (size_t)d * 256 * 1024; N = 1024; KS = 4;  dbase = 1572864 + (size_t)d * 262144;  tt = t - 32; }
    else             { src = w2     + (size_t)d * 1024 * 256; N = 256;  KS = 16; dbase = 3145728 + (size_t)d * 262144;  tt = t - 64; }
    int nb = tt / KS, ks = tt % KS;
    int k0 = ks * 64, n0 = nb * 128;
    int tid = threadIdx.x;
#pragma unroll
    for (int i = 0; i < 8; ++i) {
        int fidx = tid + i * 256;            // 0..2047 float4s of the 64x128 tile
        int kk = fidx >> 5, ng = fidx & 31;
        float4 v = *(const float4*)(src + (size_t)(k0 + kk) * N + n0 + ng * 4);
        *(float4*)&Ls[kk][ng * 4] = v;
    }
    __syncthreads();
    int n = tid & 127, kh = tid >> 7;
    ushortT* dst = out + dbase + (size_t)tt * 8192 + n * 64 + kh * 32;
    ushortT tmp[32];
#pragma unroll
    for (int j = 0; j < 32; ++j) tmp[j] = f2b(Ls[kh * 32 + j][n]);
#pragma unroll
    for (int u = 0; u < 4; ++u) *(uint4*)(dst + u * 8) = *(uint4*)(tmp + u * 8);
}

// ---------------------------------------------------------------------------
// LayerNorm: one wave per 256-float row. OB: bf16 out (for GEMM A), else fp32.
// ---------------------------------------------------------------------------
template <bool OB>
__global__ __launch_bounds__(256) void ln_kernel(const float* __restrict__ in,
                                                 void* __restrict__ out,
                                                 const float* __restrict__ s,
                                                 const float* __restrict__ b) {
    int wave = threadIdx.x >> 6;
    int lane = threadIdx.x & 63;
    size_t row = (size_t)blockIdx.x * 4 + wave;
    float4 v = reinterpret_cast<const float4*>(in + row * DMODEL)[lane];
    float sum = v.x + v.y + v.z + v.w;
    float ssq = v.x * v.x + v.y * v.y + v.z * v.z + v.w * v.w;
#pragma unroll
    for (int m = 1; m <= 32; m <<= 1) {
        sum += __shfl_xor(sum, m, 64);
        ssq += __shfl_xor(ssq, m, 64);
    }
    float mean = sum * (1.0f / 256.0f);
    float var = ssq * (1.0f / 256.0f) - mean * mean;
    float rstd = rsqrtf(var + 1e-5f);
    float4 sv = reinterpret_cast<const float4*>(s)[lane];
    float4 bv = reinterpret_cast<const float4*>(b)[lane];
    float o0 = (v.x - mean) * rstd * sv.x + bv.x;
    float o1 = (v.y - mean) * rstd * sv.y + bv.y;
    float o2 = (v.z - mean) * rstd * sv.z + bv.z;
    float o3 = (v.w - mean) * rstd * sv.w + bv.w;
    if (OB) {
        ushortT* po = (ushortT*)out + row * DMODEL + lane * 4;
        ushort4 ov; ov.x = f2b(o0); ov.y = f2b(o1); ov.z = f2b(o2); ov.w = f2b(o3);
        *(ushort4*)po = ov;
    } else {
        float4 ov; ov.x = o0; ov.y = o1; ov.z = o2; ov.w = o3;
        reinterpret_cast<float4*>((float*)out + row * DMODEL)[lane] = ov;
    }
}

// ---------------------------------------------------------------------------
// bf16 MFMA GEMM: C[M x N] = A[M x K](bf16) @ W(tiled bf16) + bias.
// 128x128 tile, BK=64, 4 waves (2x2), 4x4 16x16x32 frags per wave.
// K-loop: double-buffered LDS, staged via global_load_lds (16 B/lane DMA),
// ONE barrier per K-step; STAGE(t+1) issues before compute(t).
// Swizzle: LDS dest linear; XOR applied on the per-lane GLOBAL source column
// (unit ^= row&7) and on reads (rule #21).
// Epilogue routes C through LDS so global stores are uint4/float4
// row-contiguous (256 B per 16 lanes).
// EPI: 0 bias -> bf16 | 1 bias+gelu -> bf16 | 2 bias+residual(in-place f32 R)
// ---------------------------------------------------------------------------
template <int EPI>
__global__ __launch_bounds__(256) void gemm_bf16(const ushortT* __restrict__ A,
                                                 const ushortT* __restrict__ Wt,
                                                 const float* __restrict__ bias,
                                                 float* __restrict__ R,
                                                 ushortT* __restrict__ Cb,
                                                 int K, int N) {
    __shared__ ushortT smem[32768];      // 2 x (A 8192 | B 8192), reused as C-stage
    const int nb = blockIdx.x, n0 = nb * 128;
    const int m0 = blockIdx.y * 128;
    const int tid = threadIdx.x, lane = tid & 63, wave = tid >> 6;
    const int wr = wave >> 1, wc = wave & 1;
    const int KS = K >> 6;
    const size_t wtile = (size_t)nb * KS * 8192;

    const int rA = lane >> 3;                 // 0..7 (row within 8-row DMA group)
    const int colsw = (lane & 7) ^ rA;        // pre-swizzled source 16B unit

    // stage K-step kt into buffer buf; each wave: 4x A-DMA + 4x B-DMA (1 KB each)
    auto STAGE = [&](int buf, int kt) {
        ushortT* Ad = smem + buf * 16384;
        ushortT* Bd = Ad + 8192;
#pragma unroll
        for (int c2 = 0; c2 < 4; ++c2) {
            int rb = wave * 32 + c2 * 8;      // LDS row base (wave-uniform)
            int row = rb + rA;                // per-lane row
            gload_lds16(A + (size_t)(m0 + row) * K + kt * 64 + colsw * 8,
                        Ad + rb * 64);
            gload_lds16(Wt + wtile + (size_t)kt * 8192 + row * 64 + colsw * 8,
                        Bd + rb * 64);
        }
    };

    f32x4 acc[4][4];
#pragma unroll
    for (int i = 0; i < 4; ++i)
#pragma unroll
        for (int j = 0; j < 4; ++j) acc[i][j] = (f32x4)0.0f;

    STAGE(0, 0);
    __syncthreads();                          // drains vmcnt -> buf0 ready
    int cur = 0;
    for (int kt = 0; kt < KS; ++kt) {
        if (kt + 1 < KS) STAGE(cur ^ 1, kt + 1);   // DMA flies under MFMAs
        const ushortT* Ab = smem + cur * 16384;
        const ushortT* Bb = Ab + 8192;
#pragma unroll
        for (int kst = 0; kst < 2; ++kst) {
            frag_ab af[4], bf4[4];
            int ku = kst * 4 + (lane >> 4);
#pragma unroll
            for (int f = 0; f < 4; ++f) {
                int row = wr * 64 + f * 16 + (lane & 15);
                af[f] = *(const frag_ab*)&Ab[row * 64 + ((ku ^ (row & 7)) << 3)];
                int col = wc * 64 + f * 16 + (lane & 15);
                bf4[f] = *(const frag_ab*)&Bb[col * 64 + ((ku ^ (col & 7)) << 3)];
            }
#pragma unroll
            for (int mf = 0; mf < 4; ++mf)
#pragma unroll
                for (int nf = 0; nf < 4; ++nf)
                    acc[mf][nf] = __builtin_amdgcn_mfma_f32_16x16x32_bf16(
                        af[mf], bf4[nf], acc[mf][nf], 0, 0, 0);
        }
        __syncthreads();   // drains this step's DMA; protects buf reuse
        cur ^= 1;
    }

    // ---- epilogue via LDS transpose -> wide coalesced stores ----
    const int cg = lane >> 4, cl = lane & 15;
    if (EPI != 2) {
        ushortT* Cs = smem;   // [128][128] bf16, 16B-unit row-XOR swizzle
#pragma unroll
        for (int nf = 0; nf < 4; ++nf) {
            int col = wc * 64 + nf * 16 + cl;
            float bv = bias[n0 + col];
#pragma unroll
            for (int mf = 0; mf < 4; ++mf)
#pragma unroll
                for (int r = 0; r < 4; ++r) {
                    int row = wr * 64 + mf * 16 + cg * 4 + r;
                    float c = acc[mf][nf][r] + bv;
                    if (EPI == 1) {
                        // gelu(tanh) == x * sigmoid(1.5957691*(x+0.044715x^3))
                        c = c / (1.0f + __expf(-1.5957691216f * (c + 0.044715f * c * c * c)));
                    }
                    Cs[row * 128 + (((col >> 3) ^ (row & 7)) << 3) + (col & 7)] = f2b(c);
                }
        }
        __syncthreads();
#pragma unroll
        for (int it = 0; it < 8; ++it) {
            int idx = tid + it * 256;
            int row = idx >> 4, u = idx & 15;          // 16 lanes = 1 full row
            uint4 v = *(uint4*)&Cs[row * 128 + ((u ^ (row & 7)) << 3)];
            *(uint4*)&Cb[(size_t)(m0 + row) * N + n0 + u * 8] = v;
        }
    } else {
        float* Cf = (float*)smem;   // [64][128] fp32, float4-unit row-XOR swizzle
#pragma unroll
        for (int h = 0; h < 2; ++h) {
            if (wr == h) {
#pragma unroll
                for (int nf = 0; nf < 4; ++nf) {
                    int col = wc * 64 + nf * 16 + cl;
                    float bv = bias[n0 + col];
#pragma unroll
                    for (int mf = 0; mf < 4; ++mf)
#pragma unroll
                        for (int r = 0; r < 4; ++r) {
                            int rl = mf * 16 + cg * 4 + r;
                            Cf[rl * 128 + (((col >> 2) ^ (rl & 7)) << 2) + (col & 3)] =
                                acc[mf][nf][r] + bv;
                        }
                }
            }
            __syncthreads();
#pragma unroll
            for (int it = 0; it < 8; ++it) {
                int idx = tid + it * 256;
                int row2 = idx >> 5, u = idx & 31;     // 32 lanes = 1 full row
                float4 c4 = *(float4*)&Cf[row2 * 128 + ((u ^ (row2 & 7)) << 2)];
                float* rp = R + (size_t)(m0 + h * 64 + row2) * N + n0 + u * 4;
                float4 r4 = *(float4*)rp;
                r4.x += c4.x; r4.y += c4.y; r4.z += c4.z; r4.w += c4.w;
                *(float4*)rp = r4;
            }
            if (h == 0) __syncthreads();
        }
    }
}

// ---------------------------------------------------------------------------
// MFMA flash attention, QBLK=128 via 8-wave (512-thread) blocks.
// Block = (pair = bl*4+head, 128-row q-block); wave w owns q-rows
// i0 + w*16 .. +15 (per-wave state identical to the verified 4-wave kernel).
// Per 64-key tile: all 8 waves cooperatively stage K (XOR-swizzled) and V
// transposed (Vt[d][j], stride 72, column-XOR) in ONE pass; S = QK^T (8 MFMA);
// online softmax in exp2 domain (rel pre-scaled by log2e) with defer-max
// (THR=11.5 ~ e^8): rescale only when __all(rmax <= m+THR) fails; P packed
// via v_cvt_pk_bf16_f32 into wave-private Ps rows; O += P@V (8 MFMA).
// K/V staging + rel preload amortize over 2x the q-rows vs QBLK=64.
// LDS: Ks 8K + Vt 9K + Ps[128][64] 16K + rl 4K = 37.5 KB.
// ---------------------------------------------------------------------------
__global__ __launch_bounds__(512) void attn_kernel(const ushortT* __restrict__ qkv,
                                                   const float* __restrict__ rel,
                                                   ushortT* __restrict__ o) {
    __shared__ ushortT Ks[64 * 64];    // [j][d] swizzled: unit d>>3 ^= (j&7)
    __shared__ ushortT Vt[64 * 72];    // [d][j] transposed: j ^= ((d>>3)<<3)
    __shared__ ushortT Ps[128 * 64];   // [i][j] swizzled like Ks (wave-private rows)
    __shared__ float   rl[1024];       // rel-pos bias * log2e for this head

    const int pair = blockIdx.x, qb = blockIdx.y;
    const int bl = pair >> 2, hh = pair & 3;
    const int tid = threadIdx.x;
    const int lane = tid & 63, w = tid >> 6;       // w = 0..7
    const int c15 = lane & 15, g = lane >> 4;
    const size_t base = (size_t)bl * NSEQ * 768;
    const int qoff = hh * 64, koff = 256 + hh * 64, voff = 512 + hh * 64;
    const int i0 = qb * 128;

    for (int i = tid; i < 1023; i += 512) rl[i] = rel[(size_t)i * 4 + hh] * LOG2E;

    // Q fragments: lane holds Q[i0 + w*16 + c15][kst*32 + g*8 + jj]
    frag_ab qf[2];
    {
        const ushortT* qp = qkv + base + (size_t)(i0 + w * 16 + c15) * 768 + qoff + g * 8;
        qf[0] = *(const frag_ab*)(qp);
        qf[1] = *(const frag_ab*)(qp + 32);
    }

    float m_i[4], l_i[4];
    f32x4 oacc[4];
#pragma unroll
    for (int r = 0; r < 4; ++r) { m_i[r] = -1e30f; l_i[r] = 0.0f; }
#pragma unroll
    for (int nf = 0; nf < 4; ++nf) oacc[nf] = (f32x4)0.0f;

    const int irow = w * 16 + g * 4;          // C-layout row base (block-local)

    for (int kt = 0; kt < 8; ++kt) {
        __syncthreads();  // prev tile's frag reads done before restage
        {
            // 512 threads cover 64 keys x 8 d-groups in one pass
            int j = tid >> 3, dg = tid & 7;
            const ushortT* kp = qkv + base + (size_t)(kt * 64 + j) * 768;
            uint4 kv4 = *(const uint4*)(kp + koff + dg * 8);
            *(uint4*)&Ks[j * 64 + ((dg ^ (j & 7)) << 3)] = kv4;
            uint4 vv4 = *(const uint4*)(kp + voff + dg * 8);
            ushortT tmp[8];
            *(uint4*)tmp = vv4;
            int jc = j ^ (dg << 3);
#pragma unroll
            for (int e = 0; e < 8; ++e) Vt[(dg * 8 + e) * 72 + jc] = tmp[e];
        }
        __syncthreads();

        // ---- S = Q @ K^T (8 MFMA) ----
        f32x4 sacc[4];
#pragma unroll
        for (int nf = 0; nf < 4; ++nf) sacc[nf] = (f32x4)0.0f;
#pragma unroll
        for (int kst = 0; kst < 2; ++kst) {
            int ku = kst * 4 + g;
#pragma unroll
            for (int nf = 0; nf < 4; ++nf) {
                int j = nf * 16 + c15;
                frag_ab kf = *(frag_ab*)&Ks[j * 64 + ((ku ^ (j & 7)) << 3)];
                sacc[nf] = __builtin_amdgcn_mfma_f32_16x16x32_bf16(qf[kst], kf, sacc[nf], 0, 0, 0);
            }
        }

        // ---- online softmax, exp2 domain (row = irow + r, col = nf*16+c15) ----
        float sv[4][4];     // [nf][r]
        const int rlb = i0 + irow - kt * 64 - c15 + 511;
#pragma unroll
        for (int nf = 0; nf < 4; ++nf)
#pragma unroll
            for (int r = 0; r < 4; ++r)
                sv[nf][r] = sacc[nf][r] * (0.125f * LOG2E) + rl[rlb + r - nf * 16];

        float rmax[4];
#pragma unroll
        for (int r = 0; r < 4; ++r) {
            float rm = fmaxf(fmaxf(sv[0][r], sv[1][r]), fmaxf(sv[2][r], sv[3][r]));
#pragma unroll
            for (int m = 1; m <= 8; m <<= 1) rm = fmaxf(rm, __shfl_xor(rm, m, 64));
            rmax[r] = rm;
        }
        // defer-max: skip rescale while max growth stays under 2^11.5 (~e^8)
        bool cskip = true;
#pragma unroll
        for (int r = 0; r < 4; ++r) cskip = cskip && (rmax[r] <= m_i[r] + 11.5f);
        if (!__all(cskip)) {
#pragma unroll
            for (int r = 0; r < 4; ++r) {
                float mn = fmaxf(m_i[r], rmax[r]);
                float cr = FEXP2(m_i[r] - mn);
                m_i[r] = mn;
                l_i[r] *= cr;
#pragma unroll
                for (int nf = 0; nf < 4; ++nf) oacc[nf][r] *= cr;
            }
        }

        float psum[4] = {0.0f, 0.0f, 0.0f, 0.0f};
        unsigned int words[4][4];
#pragma unroll
        for (int nf = 0; nf < 4; ++nf)
#pragma unroll
            for (int r = 0; r < 4; ++r) {
                float p = FEXP2(sv[nf][r] - m_i[r]);
                psum[r] += p;
                float po = __shfl_xor(p, 1, 64);
                words[nf][r] = cvtpk_bf16(p, po);   // (own, neighbor) bf16 pair
            }
#pragma unroll
        for (int r = 0; r < 4; ++r) {
#pragma unroll
            for (int m = 1; m <= 8; m <<= 1) psum[r] += __shfl_xor(psum[r], m, 64);
            l_i[r] += psum[r];
        }

        // P store: even lanes write (p[j2], p[j2+1]) words, wave-private rows
        if (!(lane & 1)) {
#pragma unroll
            for (int nf = 0; nf < 4; ++nf) {
                int j2 = nf * 16 + c15;
#pragma unroll
                for (int r = 0; r < 4; ++r) {
                    int i = irow + r;
                    *(unsigned int*)&Ps[i * 64 + ((((j2 >> 3) ^ (i & 7))) << 3) + (j2 & 7)] =
                        words[nf][r];
                }
            }
        }

        // ---- O += P @ V (8 MFMA); P rows are wave-private (no barrier) ----
#pragma unroll
        for (int ks2 = 0; ks2 < 2; ++ks2) {
            int ip = w * 16 + c15;
            int jb = ks2 * 32 + g * 8;
            frag_ab pf = *(frag_ab*)&Ps[ip * 64 + (((jb >> 3) ^ (ip & 7)) << 3)];
#pragma unroll
            for (int nf = 0; nf < 4; ++nf) {
                int dh = nf * 16 + c15;
                int jv = jb ^ ((dh >> 3) << 3);
                frag_ab vf = *(frag_ab*)&Vt[dh * 72 + jv];
                oacc[nf] = __builtin_amdgcn_mfma_f32_16x16x32_bf16(pf, vf, oacc[nf], 0, 0, 0);
            }
        }
    }

    // epilogue: O /= l, pack pairs via cvt_pk, even lanes write words
    float inv[4];
#pragma unroll
    for (int r = 0; r < 4; ++r) inv[r] = 1.0f / l_i[r];
#pragma unroll
    for (int nf = 0; nf < 4; ++nf)
#pragma unroll
        for (int r = 0; r < 4; ++r) {
            float own = oacc[nf][r] * inv[r];
            float other = __shfl_xor(own, 1, 64);
            if (!(lane & 1)) {
                size_t trow = (size_t)bl * NSEQ + i0 + irow + r;
                *(unsigned int*)&o[trow * DMODEL + hh * 64 + nf * 16 + c15] =
                    cvtpk_bf16(own, other);
            }
        }
}

// ---------------------------------------------------------------------------
// Orchestration. h (residual, fp32) lives in d_out. ws layout:
//   [0, 4718592) ushorts : pre-tiled bf16 weights (9.44 MB)
//   then per-chunk scratch (bf16): xnC TCx256 | big TCx1024 (qkv 768 / mid) |
//   oC TCx256  -> TC*3072 bytes. NC chosen from ws_size only (capture-stable).
// ---------------------------------------------------------------------------
extern "C" void kernel_launch(void* const* d_in, const int* in_sizes, int n_in,
                              void* d_out, int out_size, void* d_ws, size_t ws_size,
                              hipStream_t stream) {
    const float* x       = (const float*)d_in[0];
    const float* ln1_s   = (const float*)d_in[1];
    const float* ln1_b   = (const float*)d_in[2];
    const float* qkv_w   = (const float*)d_in[3];
    const float* qkv_b   = (const float*)d_in[4];
    const float* proj_w  = (const float*)d_in[5];
    const float* proj_b  = (const float*)d_in[6];
    const float* rel_tab = (const float*)d_in[7];
    const float* ln2_s   = (const float*)d_in[8];
    const float* ln2_b   = (const float*)d_in[9];
    const float* w1      = (const float*)d_in[10];
    const float* b1      = (const float*)d_in[11];
    const float* w2      = (const float*)d_in[12];
    const float* b2      = (const float*)d_in[13];
    const float* lnf_s   = (const float*)d_in[14];
    const float* lnf_b   = (const float*)d_in[15];

    float* h = (float*)d_out;
    ushortT* wsu = (ushortT*)d_ws;
    const size_t WPRE = 4718592;  // ushorts of tiled weights

    static const int cands[12] = {1, 2, 3, 4, 6, 8, 12, 16, 24, 32, 48, 96};
    int NC = 96;
    for (int i = 0; i < 12; ++i) {
        size_t tc = (size_t)T_TOK / cands[i];
        if (WPRE * 2 + tc * 3072 <= ws_size) { NC = cands[i]; break; }
    }
    const int TC = T_TOK / NC;
    const int BLC = BLROWS / NC;
    ushortT* xnC = wsu + WPRE;
    ushortT* big = xnC + (size_t)TC * 256;
    ushortT* oC  = big + (size_t)TC * 1024;

    wprep_kernel<<<576, 256, 0, stream>>>(qkv_w, proj_w, w1, w2, wsu);
    hipMemcpyAsync(h, x, (size_t)T_TOK * DMODEL * sizeof(float),
                   hipMemcpyDeviceToDevice, stream);

    dim3 blk(256);
    for (int d = 0; d < 6; ++d) {
        for (int c = 0; c < NC; ++c) {
            float* hc = h + (size_t)c * TC * DMODEL;
            ln_kernel<true><<<TC / 4, blk, 0, stream>>>(hc, xnC, ln1_s + d * 256, ln1_b + d * 256);
            gemm_bf16<0><<<dim3(6, TC / 128), blk, 0, stream>>>(
                xnC, wsu + (size_t)d * 196608, qkv_b + d * 768, nullptr, big, 256, 768);
            attn_kernel<<<dim3(BLC * 4, NSEQ / 128), 512, 0, stream>>>(
                big, rel_tab + (size_t)d * 1023 * 4, oC);
            gemm_bf16<2><<<dim3(2, TC / 128), blk, 0, stream>>>(
                oC, wsu + 1179648 + (size_t)d * 65536, proj_b + d * 256, hc, nullptr, 256, 256);
        }
        for (int c = 0; c < NC; ++c) {
            float* hc = h + (size_t)c * TC * DMODEL;
            ln_kernel<true><<<TC / 4, blk, 0, stream>>>(hc, xnC, ln2_s + d * 256, ln2_b + d * 256);
            gemm_bf16<1><<<dim3(8, TC / 128), blk, 0, stream>>>(
                xnC, wsu + 1572864 + (size_t)d * 262144, b1 + d * 1024, nullptr, big, 256, 1024);
            gemm_bf16<2><<<dim3(2, TC / 128), blk, 0, stream>>>(
                big, wsu + 3145728 + (size_t)d * 262144, b2 + d * 256, hc, nullptr, 1024, 256);
        }
    }
    ln_kernel<false><<<T_TOK / 4, blk, 0, stream>>>(h, h, lnf_s, lnf_b);
}